// Round 6
// baseline (469.343 us; speedup 1.0000x reference)
//
#include <hip/hip_runtime.h>

#define DEV __device__ __forceinline__

typedef short bf16x8 __attribute__((ext_vector_type(8)));
typedef float f32x4 __attribute__((ext_vector_type(4)));

constexpr int BATCH = 16384, T = 64, H = 14;
constexpr float NL2E  = -1.4426950408889634f;   // -log2(e)
constexpr float N2L2E = -2.8853900817779268f;   // -2*log2(e)

union FragU { bf16x8 v; unsigned u[4]; };

DEV unsigned cvtpk(float lo, float hi) {
  unsigned r;
  asm("v_cvt_pk_bf16_f32 %0, %1, %2" : "=v"(r) : "v"(lo), "v"(hi));
  return r;
}
DEV float pklo(unsigned u) { return __uint_as_float(u << 16); }
DEV float pkhi(unsigned u) { return __uint_as_float(u & 0xffff0000u); }

DEV f32x4 MFMA(FragU a, FragU b, f32x4 c) {
  return __builtin_amdgcn_mfma_f32_16x16x32_bf16(a.v, b.v, c, 0, 0, 0);
}

// One LSTM layer; one direction per blockIdx.y; one wave = 8 sequences
// (A-frag rows 8-15 duplicate rows 0-7 -> 2x waves for latency hiding).
// Inter-layer tensors: TIME-MAJOR bf16 hi/lo planes [t][seq][16ch] per
// direction -> per-step wave writes are dense 256B bursts (full lines in L2),
// reads are dwordx4-coalesced. No LDS y-staging for bidir layers.
// h lives in LDS as 3 bf16 component planes (pre-packed frag dwords);
// hc1 slots 14,15 fixed at 1.0 -> bias rides in B there. Weights pre-scaled
// by -log2e (-2log2e for g). MFMA split into x-chain + h-chain (depth 3).
// INM: 0 = fp32 x [seq][t][13] (layer1) ; 1 = bf16 4-plane time-major x
// OUTM: 0 = bf16 4-plane time-major y ; 1 = fp32 y [seq][t][14] (layer 3)
template <int INM, int OUTM>
__global__ __launch_bounds__(256, 3) void lstm_k(
    const float* __restrict__ xf,
    const unsigned short* __restrict__ xfh, const unsigned short* __restrict__ xfl,
    const unsigned short* __restrict__ xbh, const unsigned short* __restrict__ xbl,
    const float* __restrict__ wihF, const float* __restrict__ whhF,
    const float* __restrict__ bihF, const float* __restrict__ bhhF,
    const float* __restrict__ wihB, const float* __restrict__ whhB,
    const float* __restrict__ bihB, const float* __restrict__ bhhB,
    unsigned short* __restrict__ yFh, unsigned short* __restrict__ yFl,
    unsigned short* __restrict__ yBh, unsigned short* __restrict__ yBl,
    float* __restrict__ yf)
{
  constexpr int IN = (INM == 0) ? 13 : 28;
  const int dir = (OUTM == 1) ? 0 : blockIdx.y;
  const float* __restrict__ wih = dir ? wihB : wihF;
  const float* __restrict__ whh = dir ? whhB : whhF;
  const float* __restrict__ bih = dir ? bihB : bihF;
  const float* __restrict__ bhh = dir ? bhhB : bhhF;
  unsigned short* __restrict__ yhiP = dir ? yBh : yFh;
  unsigned short* __restrict__ yloP = dir ? yBl : yFl;

  const int tid = threadIdx.x;
  const int w = tid >> 6, lane = tid & 63;
  const int col = lane & 15, q = lane >> 4;
  const int qodd = q & 1, qhi = q >> 1;
  const int sc8 = col & 7;           // this lane's seq-in-wave (A side)
  const bool jv = col < H;
  const int jc = jv ? col : 13;

  // per (wave, seq<8): hc1[8] | hc2[8] | hc3[8] | pad[4] dwords (stride 28)
  __shared__ unsigned hlds[4][8][28];                         // 3584 B
  __shared__ __align__(16) float fst_s[(OUTM == 1) ? 4 * 16 * 8 * 16 : 4];
  {
    unsigned* hb = &hlds[w][0][0];
    for (int i = lane; i < 224; i += 64) hb[i] = ((i % 28) == 7) ? 0x3F803F80u : 0u;
  }

  // ---------------- B fragments (built once, pre-scaled) ----------------
  FragU Bx1[4], Bx2[4], Bh1[4], Bh2[4], Bh3[4];
#pragma unroll
  for (int g = 0; g < 4; ++g) {
    const int grow = g * H + jc;
    const float sc = (g == 2) ? N2L2E : NL2E;
    const float bsc = (bih[grow] + bhh[grow]) * sc;
    const unsigned bq1 = cvtpk(bsc, bsc);
    const float br1 = bsc - pklo(bq1);
    const unsigned bq2 = cvtpk(br1, br1);
    const float br2 = br1 - pklo(bq2);
    const unsigned bP12 = cvtpk(bsc, br1);   // (b1, b2)
    const unsigned bP30 = cvtpk(br2, 0.f);   // (b3, 0)
    const float* __restrict__ wr = wih + grow * IN;
    const float* __restrict__ ur = whh + grow * H;
#pragma unroll
    for (int p = 0; p < 4; ++p) {
      {  // x weights
        float wa = 0.f, wb = 0.f;
        const int l0 = 8 * qodd + 2 * p;
        if (INM == 0) {  // 13 ch; sec0 = values, sec1 = residual components
          if (jv && l0 < 13) wa = wr[l0] * sc;
          if (jv && l0 + 1 < 13) wb = wr[l0 + 1] * sc;
        } else {         // plane-local ch l; wih col = qhi*14 + l
          if (jv && l0 < 14) wa = wr[qhi * 14 + l0] * sc;
          if (jv && l0 + 1 < 14) wb = wr[qhi * 14 + l0 + 1] * sc;
        }
        const unsigned c1 = cvtpk(wa, wb);
        const float ra = wa - pklo(c1), rb = wb - pkhi(c1);
        const unsigned c2 = cvtpk(ra, rb);
        Bx1[g].u[p] = c1;
        Bx2[g].u[p] = (INM == 0 && qhi) ? 0u : c2;  // L1: sec1 of Bx2 = 0
      }
      {  // h weights: Bh1=[U1|U1](+b1,b2), Bh2=[U2|U2](+b3), Bh3=[U3|U1]
        const int m0 = 8 * qodd + 2 * p;
        const float ua = (jv && m0 < 14) ? ur[m0] * sc : 0.f;
        const float ub = (jv && (m0 + 1) < 14) ? ur[m0 + 1] * sc : 0.f;
        const unsigned c1 = cvtpk(ua, ub);
        const float ra = ua - pklo(c1), rb = ub - pkhi(c1);
        const unsigned c2 = cvtpk(ra, rb);
        const float ra2 = ra - pklo(c2), rb2 = rb - pkhi(c2);
        const unsigned c3 = cvtpk(ra2, rb2);
        unsigned h1 = c1, h2 = c2, h3 = qhi ? c1 : c3;
        if (q == 1 && p == 3) {  // sec0 slots 14,15: bias carriers (A = 1.0)
          h1 = jv ? bP12 : 0u; h2 = jv ? bP30 : 0u; h3 = 0u;
        }
        Bh1[g].u[p] = h1; Bh2[g].u[p] = h2; Bh3[g].u[p] = h3;
      }
    }
  }

  const unsigned sb = (unsigned)blockIdx.x * 32u + (unsigned)w * 8u;

  // static LDS read pointers (A12: hc1/hc2 ; A13: hc1/hc3)
  const unsigned hbase = (unsigned)((w * 8 + sc8) * 28);
  const uint4* __restrict__ rp12 =
      (const uint4*)(&hlds[0][0][0] + hbase + (qhi ? 8 : 0) + qodd * 4);
  const uint4* __restrict__ rp13 =
      (const uint4*)(&hlds[0][0][0] + hbase + (qhi ? 16 : 0) + qodd * 4);

  // static LDS write pointers for h (q<2 lanes own seqs 4q+i)
  unsigned short* hw[4];
#pragma unroll
  for (int i = 0; i < 4; ++i)
    hw[i] = (unsigned short*)(&hlds[w][4 * (q & 1) + i][0]) + col;

  const int t0 = dir ? T - 1 : 0;
  constexpr int ROWX1 = 52;        // L1: bytes per fp32 x row
  const int dsx = (INM == 0) ? (dir ? -ROWX1 : ROWX1) : (dir ? -524288 : 524288);
  const int dyy = dir ? -524288 : 524288;
  unsigned voffx;
  if constexpr (INM == 0)
    voffx = (unsigned)(((sb + sc8) * T + (unsigned)t0) * ROWX1) + (unsigned)(qodd * 32);
  else
    voffx = ((unsigned)t0 * 16384u + sb + (unsigned)sc8) * 32u + (unsigned)(qodd * 16);
  unsigned yoff = ((unsigned)t0 * 16384u + sb + 4u * (unsigned)(q & 1)) * 32u +
                  (unsigned)(col * 2);
  const unsigned short* __restrict__ xph = (INM == 0) ? nullptr : (qhi ? xbh : xfh);
  const unsigned short* __restrict__ xpl = (INM == 0) ? nullptr : (qhi ? xbl : xfl);
  float* __restrict__ fst = fst_s + w * 2048;  // [16t][8seq][16] (OUTM==1)

  float cc[4] = {0.f, 0.f, 0.f, 0.f};

  auto loadf = [&](float (&dst)[8], unsigned off) {
    const float* pa = (const float*)((const char*)xf + off);
    if (!qodd) {
#pragma unroll
      for (int e = 0; e < 8; ++e) dst[e] = pa[e];
    } else {  // l = 8..12 valid; clamp tail (B-side zeros kill the clones)
#pragma unroll
      for (int e = 0; e < 5; ++e) dst[e] = pa[e];
      dst[5] = dst[6] = dst[7] = dst[4];
    }
  };
  auto loadu = [&](unsigned (&dst)[8], unsigned off) {
    const uint4 a = *(const uint4*)((const char*)xph + off);
    const uint4 b = *(const uint4*)((const char*)xpl + off);
    dst[0] = a.x; dst[1] = a.y; dst[2] = a.z; dst[3] = a.w;
    dst[4] = b.x; dst[5] = b.y; dst[6] = b.z; dst[7] = b.w;
  };

  auto STEP = [&](int t, float (&xfb)[8], unsigned (&xub)[8]) {
    // h fragments straight from LDS (pre-packed components)
    FragU A12, A13;
    { const uint4 t4 = *rp12; A12.u[0]=t4.x; A12.u[1]=t4.y; A12.u[2]=t4.z; A12.u[3]=t4.w; }
    { const uint4 t4 = *rp13; A13.u[0]=t4.x; A13.u[1]=t4.y; A13.u[2]=t4.z; A13.u[3]=t4.w; }
    // x fragments
    FragU Ax1, Ax2;
    if constexpr (INM == 0) {
      unsigned c[4];
#pragma unroll
      for (int p = 0; p < 4; ++p) c[p] = cvtpk(xfb[2 * p], xfb[2 * p + 1]);
      if (qhi) {  // sec1 lanes carry the residual component
#pragma unroll
        for (int p = 0; p < 4; ++p) {
          const float ra = xfb[2 * p] - pklo(c[p]);
          const float rb = xfb[2 * p + 1] - pkhi(c[p]);
          c[p] = cvtpk(ra, rb);
        }
      }
#pragma unroll
      for (int p = 0; p < 4; ++p) Ax1.u[p] = c[p];
    } else {
#pragma unroll
      for (int p = 0; p < 4; ++p) { Ax1.u[p] = xub[p]; Ax2.u[p] = xub[4 + p]; }
    }
    // MFMAs: two independent depth-3 chains per gate (x-chain, h-chain)
    f32x4 aX[4], aH[4];
#pragma unroll
    for (int g = 0; g < 4; ++g) {
      f32x4 ax = {0.f, 0.f, 0.f, 0.f};
      ax = MFMA(Ax1, Bx1[g], ax);        // x1W1 (+x2W1 for L1)
      if constexpr (INM == 0) {
        ax = MFMA(Ax1, Bx2[g], ax);      // x1W2
      } else {
        ax = MFMA(Ax2, Bx1[g], ax);      // x2W1
        ax = MFMA(Ax1, Bx2[g], ax);      // x1W2
      }
      f32x4 ah = {0.f, 0.f, 0.f, 0.f};
      ah = MFMA(A12, Bh1[g], ah);        // h1U1 + h2U1 + b1 + b2
      ah = MFMA(A12, Bh2[g], ah);        // h1U2 + h2U2 + b3
      ah = MFMA(A13, Bh3[g], ah);        // h1U3 + h3U1
      aX[g] = ax; aH[g] = ah;
    }
    // scalar epilogue: only lanes owning valid C rows (q < 2)
    if (q < 2) {
      const int ts = t & 15;
#pragma unroll
      for (int i = 0; i < 4; ++i) {
        const float zi = aX[0][i] + aH[0][i];
        const float zf = aX[1][i] + aH[1][i];
        const float zg = aX[2][i] + aH[2][i];
        const float zo = aX[3][i] + aH[3][i];
        const float Ei = __builtin_amdgcn_exp2f(zi);
        const float Ef = __builtin_amdgcn_exp2f(zf);
        const float Eo = __builtin_amdgcn_exp2f(zo);
        const float Eg = __builtin_amdgcn_exp2f(-fabsf(zg));
        float u = (1.f - Eg) * __builtin_amdgcn_rcpf((1.f + Ei) * (1.f + Eg));
        u = copysignf(u, __uint_as_float(__float_as_uint(zg) ^ 0x80000000u));
        const float cn = fmaf(cc[i], __builtin_amdgcn_rcpf(1.f + Ef), u);
        cc[i] = cn;
        const float Ec = __builtin_amdgcn_exp2f(fabsf(cn) * N2L2E);
        float hn = (1.f - Ec) * __builtin_amdgcn_rcpf((1.f + Eo) * (1.f + Ec));
        hn = copysignf(hn, cn);
        // 3-way split of h -> bf16 components
        const unsigned c1 = cvtpk(hn, hn);
        const float r1 = hn - pklo(c1);
        const unsigned c2 = cvtpk(r1, r1);
        const float r2 = r1 - pklo(c2);
        const unsigned c3 = cvtpk(r2, r2);
        if (jv) {
          hw[i][0]  = (unsigned short)c1;
          hw[i][16] = (unsigned short)c2;
          hw[i][32] = (unsigned short)c3;
          if constexpr (OUTM == 0) {
            *(unsigned short*)((char*)yhiP + yoff + i * 32) = (unsigned short)c1;
            *(unsigned short*)((char*)yloP + yoff + i * 32) = (unsigned short)c2;
          } else {
            fst[(ts * 8 + 4 * q + i) * 16 + col] = hn;
          }
        }
      }
      if constexpr (OUTM == 0) yoff += (unsigned)dyy;
    }
  };

  const int sq = lane >> 3, part = lane & 7;  // flush roles (OUTM==1)
  auto flushO = [&](int tbase) {  // 896B per seq = 14 full 64B lines
    union { float f[28]; uint4 v[7]; } ub;
#pragma unroll
    for (int r = 0; r < 2; ++r) {
      const float* src = fst + ((2 * part + r) * 8 + sq) * 16;
      const float4 a0 = *(const float4*)(src);
      const float4 a1 = *(const float4*)(src + 4);
      const float4 a2 = *(const float4*)(src + 8);
      const float2 a3 = *(const float2*)(src + 12);
      const int o = r * 14;
      ub.f[o+0]=a0.x; ub.f[o+1]=a0.y; ub.f[o+2]=a0.z; ub.f[o+3]=a0.w;
      ub.f[o+4]=a1.x; ub.f[o+5]=a1.y; ub.f[o+6]=a1.z; ub.f[o+7]=a1.w;
      ub.f[o+8]=a2.x; ub.f[o+9]=a2.y; ub.f[o+10]=a2.z; ub.f[o+11]=a2.w;
      ub.f[o+12]=a3.x; ub.f[o+13]=a3.y;
    }
    char* gp = (char*)yf +
               ((sb + (unsigned)sq) * 64u + (unsigned)(tbase + 2 * part)) * 56u;
#pragma unroll
    for (int m = 0; m < 7; ++m) *(uint4*)(gp + m * 16) = ub.v[m];
  };

  float bufAf[8], bufBf[8];
  unsigned bufAu[8], bufBu[8];
  if constexpr (INM == 0) loadf(bufAf, voffx); else loadu(bufAu, voffx);
#pragma unroll 1
  for (int s = 0; s < T; s += 2) {
    const int ta = dir ? T - 1 - s : s;
    const int tb = dir ? T - 2 - s : s + 1;
    const unsigned vb = voffx + (unsigned)dsx;
    if constexpr (INM == 0) loadf(bufBf, vb); else loadu(bufBu, vb);
    STEP(ta, bufAf, bufAu);
    const unsigned va = (s + 2 < T) ? vb + (unsigned)dsx : vb;
    if constexpr (INM == 0) loadf(bufAf, va); else loadu(bufAu, va);
    STEP(tb, bufBf, bufBu);
    voffx = va;
    if constexpr (OUTM == 1) {
      if ((s & 15) == 14) flushO(tb & ~15);
    }
  }
}

extern "C" void kernel_launch(void* const* d_in, const int* in_sizes, int n_in,
                              void* d_out, int out_size, void* d_ws, size_t ws_size,
                              hipStream_t stream) {
  const float* x     = (const float*)d_in[0];
  const float* wih1f = (const float*)d_in[1];
  const float* whh1f = (const float*)d_in[2];
  const float* bih1f = (const float*)d_in[3];
  const float* bhh1f = (const float*)d_in[4];
  const float* wih1b = (const float*)d_in[5];
  const float* whh1b = (const float*)d_in[6];
  const float* bih1b = (const float*)d_in[7];
  const float* bhh1b = (const float*)d_in[8];
  const float* wih2f = (const float*)d_in[9];
  const float* whh2f = (const float*)d_in[10];
  const float* bih2f = (const float*)d_in[11];
  const float* bhh2f = (const float*)d_in[12];
  const float* wih2b = (const float*)d_in[13];
  const float* whh2b = (const float*)d_in[14];
  const float* bih2b = (const float*)d_in[15];
  const float* bhh2b = (const float*)d_in[16];
  const float* wih3  = (const float*)d_in[17];
  const float* whh3  = (const float*)d_in[18];
  const float* bih3  = (const float*)d_in[19];
  const float* bhh3  = (const float*)d_in[20];

  using usp = unsigned short*;
  const size_t PL = (size_t)BATCH * T * 16;  // ushorts per time-major plane
  usp y1fh = (usp)d_ws;
  usp y1fl = y1fh + PL;
  usp y1bh = y1fl + PL;
  usp y1bl = y1bh + PL;
  usp y2fh = y1bl + PL;
  usp y2fl = y2fh + PL;
  usp y2bh = y2fl + PL;
  usp y2bl = y2bh + PL;
  float* out = (float*)d_out;

  const dim3 blk(256);
  const dim3 grid_bi(BATCH / 32, 2);
  const dim3 grid_uni(BATCH / 32, 1);

  lstm_k<0, 0><<<grid_bi, blk, 0, stream>>>(
      x, nullptr, nullptr, nullptr, nullptr,
      wih1f, whh1f, bih1f, bhh1f, wih1b, whh1b, bih1b, bhh1b,
      y1fh, y1fl, y1bh, y1bl, nullptr);
  lstm_k<1, 0><<<grid_bi, blk, 0, stream>>>(
      nullptr, y1fh, y1fl, y1bh, y1bl,
      wih2f, whh2f, bih2f, bhh2f, wih2b, whh2b, bih2b, bhh2b,
      y2fh, y2fl, y2bh, y2bl, nullptr);
  lstm_k<1, 1><<<grid_uni, blk, 0, stream>>>(
      nullptr, y2fh, y2fl, y2bh, y2bl,
      wih3, whh3, bih3, bhh3, wih3, whh3, bih3, bhh3,
      nullptr, nullptr, nullptr, nullptr, out);
}

// Round 8
// 340.008 us; speedup vs baseline: 1.3804x; 1.3804x over previous
//
#include <hip/hip_runtime.h>

#define DEV __device__ __forceinline__

typedef short bf16x8 __attribute__((ext_vector_type(8)));
typedef float f32x4 __attribute__((ext_vector_type(4)));

constexpr int BATCH = 16384, T = 64, H = 14;
constexpr float NL2E  = -1.4426950408889634f;   // -log2(e)
constexpr float N2L2E = -2.8853900817779268f;   // -2*log2(e)

union FragU { bf16x8 v; unsigned u[4]; };

DEV unsigned cvtpk(float lo, float hi) {
  unsigned r;
  asm("v_cvt_pk_bf16_f32 %0, %1, %2" : "=v"(r) : "v"(lo), "v"(hi));
  return r;
}
DEV float pklo(unsigned u) { return __uint_as_float(u << 16); }
DEV float pkhi(unsigned u) { return __uint_as_float(u & 0xffff0000u); }

// asm MFMA, hazard-guarded: s_nop 1 (2 wait states) covers any preceding
// VALU write of an operand reg (compiler can't see inside asm to do it).
DEV void MFMA_acc(f32x4& c, bf16x8 a, bf16x8 b) {
  asm("s_nop 1\n\tv_mfma_f32_16x16x32_bf16 %0, %1, %2, %0"
      : "+v"(c) : "v"(a), "v"(b));
}
// chain head: D = A*B + C0 (C0 = persistent zero quad; no per-step v_mov init)
DEV f32x4 MFMA_first(bf16x8 a, bf16x8 b, f32x4 c0) {
  f32x4 d;
  asm("s_nop 1\n\tv_mfma_f32_16x16x32_bf16 %0, %1, %2, %3"
      : "=&v"(d) : "v"(a), "v"(b), "v"(c0));
  return d;
}

// One LSTM layer; one direction per blockIdx.y; one wave = 16 sequences.
// Inter-layer tensors: per-direction bf16 hi/lo planes [seq][t][16ch] (32B
// rows). y staged in LDS, flushed every 8 steps as full-line dwordx4 bursts.
// h in LDS as 3 bf16 component planes (pre-packed frag dwords); hc1 slots
// 14,15 fixed at 1.0 -> bias rides in B there. Weights pre-scaled by -log2e
// (-2log2e for g). x prefetched 2 steps ahead (4 rotating buffers).
// INM: 0 = fp32 x [seq][t][13] (layer1) ; 1 = bf16 4-plane x (layers 2,3)
// OUTM: 0 = bf16 4-plane y ; 1 = fp32 y [seq][t][14] (layer 3)
template <int INM, int OUTM>
__global__ __launch_bounds__(256, 2) void lstm_k(
    const float* __restrict__ xf,
    const unsigned short* __restrict__ xfh, const unsigned short* __restrict__ xfl,
    const unsigned short* __restrict__ xbh, const unsigned short* __restrict__ xbl,
    const float* __restrict__ wihF, const float* __restrict__ whhF,
    const float* __restrict__ bihF, const float* __restrict__ bhhF,
    const float* __restrict__ wihB, const float* __restrict__ whhB,
    const float* __restrict__ bihB, const float* __restrict__ bhhB,
    unsigned short* __restrict__ yFh, unsigned short* __restrict__ yFl,
    unsigned short* __restrict__ yBh, unsigned short* __restrict__ yBl,
    float* __restrict__ yf)
{
  constexpr int IN = (INM == 0) ? 13 : 28;
  const int dir = (OUTM == 1) ? 0 : blockIdx.y;
  const float* __restrict__ wih = dir ? wihB : wihF;
  const float* __restrict__ whh = dir ? whhB : whhF;
  const float* __restrict__ bih = dir ? bihB : bihF;
  const float* __restrict__ bhh = dir ? bhhB : bhhF;
  unsigned short* __restrict__ yhiP = dir ? yBh : yFh;
  unsigned short* __restrict__ yloP = dir ? yBl : yFl;

  const int tid = threadIdx.x;
  const int w = tid >> 6, lane = tid & 63;
  const int col = lane & 15, q = lane >> 4;
  const int qodd = q & 1, qhi = q >> 1;
  const bool jv = col < H;
  const int jc = jv ? col : 13;

  // per (wave, seq): hc1[8] | hc2[8] | hc3[8] | pad[4] dwords (stride 28)
  __shared__ unsigned hlds[4][16][28];  // 7168 B
  __shared__ __align__(16) unsigned short
      yst[OUTM == 0 ? 4 : 1][2][OUTM == 0 ? 8 : 1][16][16];     // 16 KB / 1 KB
  __shared__ __align__(16) float fst_s[OUTM == 1 ? 4 * 16 * 8 * 14 : 4];
  float* __restrict__ fstw = fst_s + ((OUTM == 1) ? w * 1792 : 0);
  {
    unsigned* hb = &hlds[w][0][0];
    for (int i = lane; i < 448; i += 64) hb[i] = ((i % 28) == 7) ? 0x3F803F80u : 0u;
  }

  // persistent zero accumulator seed (opaque so it can't be rematerialized)
  f32x4 zv = {0.f, 0.f, 0.f, 0.f};
  asm("" : "+v"(zv));

  // ---------------- B fragments (built once, pre-scaled) ----------------
  FragU Bx1[4], Bx2[4], Bh1[4], Bh2[4], Bh3[4];
#pragma unroll
  for (int g = 0; g < 4; ++g) {
    const int grow = g * H + jc;
    const float sc = (g == 2) ? N2L2E : NL2E;
    const float bsc = (bih[grow] + bhh[grow]) * sc;
    const unsigned bq1 = cvtpk(bsc, bsc);
    const float br1 = bsc - pklo(bq1);
    const unsigned bq2 = cvtpk(br1, br1);
    const float br2 = br1 - pklo(bq2);
    const unsigned bP12 = cvtpk(bsc, br1);   // (b1, b2)
    const unsigned bP30 = cvtpk(br2, 0.f);   // (b3, 0)
    const float* __restrict__ wr = wih + grow * IN;
    const float* __restrict__ ur = whh + grow * H;
#pragma unroll
    for (int p = 0; p < 4; ++p) {
      {  // x weights
        float wa = 0.f, wb = 0.f;
        const int l0 = 8 * qodd + 2 * p;
        if (INM == 0) {  // 13 ch; sec0 = values, sec1 = residual components
          if (jv && l0 < 13) wa = wr[l0] * sc;
          if (jv && l0 + 1 < 13) wb = wr[l0 + 1] * sc;
        } else {         // plane-local ch l; wih col = qhi*14 + l
          if (jv && l0 < 14) wa = wr[qhi * 14 + l0] * sc;
          if (jv && l0 + 1 < 14) wb = wr[qhi * 14 + l0 + 1] * sc;
        }
        const unsigned c1 = cvtpk(wa, wb);
        const float ra = wa - pklo(c1), rb = wb - pkhi(c1);
        const unsigned c2 = cvtpk(ra, rb);
        Bx1[g].u[p] = c1;
        Bx2[g].u[p] = (INM == 0 && qhi) ? 0u : c2;  // L1: sec1 of Bx2 = 0
      }
      {  // h weights: Bh1=[U1|U1](+b1,b2), Bh2=[U2|U2](+b3), Bh3=[U3|U1]
        const int m0 = 8 * qodd + 2 * p;
        const float ua = (jv && m0 < 14) ? ur[m0] * sc : 0.f;
        const float ub = (jv && (m0 + 1) < 14) ? ur[m0 + 1] * sc : 0.f;
        const unsigned c1 = cvtpk(ua, ub);
        const float ra = ua - pklo(c1), rb = ub - pkhi(c1);
        const unsigned c2 = cvtpk(ra, rb);
        const float ra2 = ra - pklo(c2), rb2 = rb - pkhi(c2);
        const unsigned c3 = cvtpk(ra2, rb2);
        unsigned h1 = c1, h2 = c2, h3 = qhi ? c1 : c3;
        if (q == 1 && p == 3) {  // sec0 slots 14,15: bias carriers (A = 1.0)
          h1 = jv ? bP12 : 0u; h2 = jv ? bP30 : 0u; h3 = 0u;
        }
        Bh1[g].u[p] = h1; Bh2[g].u[p] = h2; Bh3[g].u[p] = h3;
      }
    }
  }

  const unsigned sb = (unsigned)blockIdx.x * 64u + (unsigned)w * 16u;
  const unsigned arow = sb + (unsigned)col;  // this lane's seq for the A side

  // static LDS read pointers (A12: hc1/hc2 ; A13: hc1/hc3)
  const unsigned hbase = (unsigned)((w * 16 + col) * 28);
  const uint4* __restrict__ rp12 =
      (const uint4*)(&hlds[0][0][0] + hbase + (qhi ? 8 : 0) + qodd * 4);
  const uint4* __restrict__ rp13 =
      (const uint4*)(&hlds[0][0][0] + hbase + (qhi ? 16 : 0) + qodd * 4);

  // static LDS write pointers for h (one per owned seq)
  unsigned short* hw[4];
#pragma unroll
  for (int i = 0; i < 4; ++i)
    hw[i] = (unsigned short*)(&hlds[w][4 * q + i][0]) + col;

  const int t0 = dir ? T - 1 : 0;
  constexpr int ROWX = (INM == 0) ? 52 : 32;  // bytes per x row (per plane)
  const int dsx = dir ? -ROWX : ROWX;
  unsigned voff0;
  if constexpr (INM == 0)
    voff0 = (arow * 64u + (unsigned)t0) * 52u + (unsigned)(qodd * 32);
  else
    voff0 = (arow * 64u + (unsigned)t0) * 32u + (unsigned)(qodd * 16);
  const unsigned short* __restrict__ xph = (INM == 0) ? nullptr : (qhi ? xbh : xfh);
  const unsigned short* __restrict__ xpl = (INM == 0) ? nullptr : (qhi ? xbl : xfl);

  float cc[4] = {0.f, 0.f, 0.f, 0.f};

  auto loadf = [&](float (&dst)[8], unsigned off) {
    const float* pa = (const float*)((const char*)xf + off);
    if (!qodd) {
#pragma unroll
      for (int e = 0; e < 8; ++e) dst[e] = pa[e];
    } else {  // l = 8..12 valid; clamp tail (B-side zeros kill the clones)
#pragma unroll
      for (int e = 0; e < 5; ++e) dst[e] = pa[e];
      dst[5] = dst[6] = dst[7] = dst[4];
    }
  };
  auto loadu = [&](unsigned (&dst)[8], unsigned off) {
    const uint4 a = *(const uint4*)((const char*)xph + off);
    const uint4 b = *(const uint4*)((const char*)xpl + off);
    dst[0] = a.x; dst[1] = a.y; dst[2] = a.z; dst[3] = a.w;
    dst[4] = b.x; dst[5] = b.y; dst[6] = b.z; dst[7] = b.w;
  };
  auto LOADX = [&](float (&df)[8], unsigned (&du)[8], unsigned off) {
    if constexpr (INM == 0) loadf(df, off); else loadu(du, off);
  };

  auto STEP = [&](int t, float (&xfb)[8], unsigned (&xub)[8]) {
    // h fragments straight from LDS (pre-packed components)
    FragU A12, A13;
    { const uint4 t4 = *rp12; A12.u[0]=t4.x; A12.u[1]=t4.y; A12.u[2]=t4.z; A12.u[3]=t4.w; }
    { const uint4 t4 = *rp13; A13.u[0]=t4.x; A13.u[1]=t4.y; A13.u[2]=t4.z; A13.u[3]=t4.w; }
    // x fragments
    FragU Ax1, Ax2;
    if constexpr (INM == 0) {
      unsigned c[4];
#pragma unroll
      for (int p = 0; p < 4; ++p) c[p] = cvtpk(xfb[2 * p], xfb[2 * p + 1]);
      if (qhi) {  // sec1 lanes carry the residual component
#pragma unroll
        for (int p = 0; p < 4; ++p) {
          const float ra = xfb[2 * p] - pklo(c[p]);
          const float rb = xfb[2 * p + 1] - pkhi(c[p]);
          c[p] = cvtpk(ra, rb);
        }
      }
#pragma unroll
      for (int p = 0; p < 4; ++p) Ax1.u[p] = c[p];
    } else {
#pragma unroll
      for (int p = 0; p < 4; ++p) { Ax1.u[p] = xub[p]; Ax2.u[p] = xub[4 + p]; }
    }
    // MFMAs: independent x-chain + h-chain per gate (depth <= 3)
    f32x4 aX[4], aH[4];
#pragma unroll
    for (int g = 0; g < 4; ++g) {
      f32x4 ax = MFMA_first(Ax1.v, Bx1[g].v, zv);   // x1W1 (+x2W1 for L1)
      if constexpr (INM == 0) {
        MFMA_acc(ax, Ax1.v, Bx2[g].v);              // x1W2
      } else {
        MFMA_acc(ax, Ax2.v, Bx1[g].v);              // x2W1
        MFMA_acc(ax, Ax1.v, Bx2[g].v);              // x1W2
      }
      f32x4 ah = MFMA_first(A12.v, Bh1[g].v, zv);   // h1U1 + h2U1 + b1 + b2
      MFMA_acc(ah, A12.v, Bh2[g].v);                // h1U2 + h2U2 + b3
      MFMA_acc(ah, A13.v, Bh3[g].v);                // h1U3 + h3U1
      aX[g] = ax; aH[g] = ah;
    }
    // dependency-tied hazard fence: MFMA write -> VALU read needs wait states;
    // activations consume the "+v" outputs so they cannot be hoisted above it.
    asm("s_nop 7\n\ts_nop 7"
        : "+v"(aX[0]), "+v"(aX[1]), "+v"(aX[2]), "+v"(aX[3]),
          "+v"(aH[0]), "+v"(aH[1]), "+v"(aH[2]), "+v"(aH[3]));
    // activations (weights pre-scaled: z' = -log2e*z ; g: -2log2e*z)
    const int ts = t & 7;
#pragma unroll
    for (int i = 0; i < 4; ++i) {
      const float zi = aX[0][i] + aH[0][i];
      const float zf = aX[1][i] + aH[1][i];
      const float zg = aX[2][i] + aH[2][i];
      const float zo = aX[3][i] + aH[3][i];
      const float Ei = __builtin_amdgcn_exp2f(zi);
      const float Ef = __builtin_amdgcn_exp2f(zf);
      const float Eo = __builtin_amdgcn_exp2f(zo);
      const float Eg = __builtin_amdgcn_exp2f(-fabsf(zg));
      float u = (1.f - Eg) * __builtin_amdgcn_rcpf((1.f + Ei) * (1.f + Eg));
      u = copysignf(u, __uint_as_float(__float_as_uint(zg) ^ 0x80000000u));
      const float cn = fmaf(cc[i], __builtin_amdgcn_rcpf(1.f + Ef), u);
      cc[i] = cn;
      const float Ec = __builtin_amdgcn_exp2f(fabsf(cn) * N2L2E);
      float hn = (1.f - Ec) * __builtin_amdgcn_rcpf((1.f + Eo) * (1.f + Ec));
      hn = copysignf(hn, cn);
      // 3-way split of h -> bf16 components
      const unsigned c1 = cvtpk(hn, hn);
      const float r1 = hn - pklo(c1);
      const unsigned c2 = cvtpk(r1, r1);
      const float r2 = r1 - pklo(c2);
      const unsigned c3 = cvtpk(r2, r2);
      if (jv) {
        hw[i][0]  = (unsigned short)c1;
        hw[i][16] = (unsigned short)c2;
        hw[i][32] = (unsigned short)c3;
        if constexpr (OUTM == 0) {
          yst[w][0][ts][4 * q + i][col] = (unsigned short)c1;
          yst[w][1][ts][4 * q + i][col] = (unsigned short)c2;
        } else {
          fstw[(4 * q + i) * 112 + ts * 14 + col] = hn;
        }
      } else {
        if constexpr (OUTM == 0) {  // zero pad channels
          yst[w][0][ts][4 * q + i][col] = 0;
          yst[w][1][ts][4 * q + i][col] = 0;
        }
      }
    }
  };

  auto flushY = [&](int tbase) {  // 8t x 16ch x 2B = 256B/seq/plane, full lines
    const int sq = lane >> 2, part = lane & 3;
    const unsigned rowb = (sb + (unsigned)sq) * 64u + (unsigned)tbase;
#pragma unroll
    for (int pl = 0; pl < 2; ++pl) {
      char* gp0 = (char*)(pl ? yloP : yhiP);
#pragma unroll
      for (int r = 0; r < 2; ++r) {
        const int tt = 2 * part + r;
        const uint4 v0 = *(const uint4*)&yst[w][pl][tt][sq][0];
        const uint4 v1 = *(const uint4*)&yst[w][pl][tt][sq][8];
        char* gp = gp0 + (rowb + (unsigned)tt) * 32u;
        *(uint4*)(gp) = v0;
        *(uint4*)(gp + 16) = v1;
      }
    }
  };
  auto flushO = [&](int tbase) {  // 8t x 14f = 448B/seq contiguous, 16B aligned
    const int sq = lane >> 2, p = lane & 3;
    const float* src = fstw + sq * 112 + p * 28;
    uint4 vv[7];
#pragma unroll
    for (int m = 0; m < 7; ++m) vv[m] = *(const uint4*)(src + m * 4);
    char* gp = (char*)yf + ((sb + (unsigned)sq) * 64u + (unsigned)tbase) * 56u +
               (unsigned)(p * 112);
#pragma unroll
    for (int m = 0; m < 7; ++m) *(uint4*)(gp + m * 16) = vv[m];
  };

  auto tj = [&](int j) { return dir ? T - 1 - j : j; };

  float fA[8], fB[8], fC[8], fD[8];
  unsigned uA[8], uB[8], uC[8], uD[8];
  unsigned vA = voff0, vB = voff0 + (unsigned)dsx;
  LOADX(fA, uA, vA);
  LOADX(fB, uB, vB);
  unsigned vLast = vB;
#pragma unroll 1
  for (int s = 0; s < T; s += 4) {
    const unsigned vC = vLast + (unsigned)dsx;
    const unsigned vD = vC + (unsigned)dsx;
    LOADX(fC, uC, vC);
    LOADX(fD, uD, vD);
    STEP(tj(s), fA, uA);
    STEP(tj(s + 1), fB, uB);
    unsigned vE = vD;
    if (s + 4 < T) {
      const unsigned vA2 = vD + (unsigned)dsx;
      const unsigned vB2 = vA2 + (unsigned)dsx;
      LOADX(fA, uA, vA2);
      LOADX(fB, uB, vB2);
      vE = vB2;
    }
    STEP(tj(s + 2), fC, uC);
    STEP(tj(s + 3), fD, uD);
    vLast = vE;
    if ((s & 7) == 4) {
      const int tbase = dir ? (T - 8 - (s - 4)) : (s - 4);
      if constexpr (OUTM == 0) flushY(tbase); else flushO(tbase);
    }
  }
}

extern "C" void kernel_launch(void* const* d_in, const int* in_sizes, int n_in,
                              void* d_out, int out_size, void* d_ws, size_t ws_size,
                              hipStream_t stream) {
  const float* x     = (const float*)d_in[0];
  const float* wih1f = (const float*)d_in[1];
  const float* whh1f = (const float*)d_in[2];
  const float* bih1f = (const float*)d_in[3];
  const float* bhh1f = (const float*)d_in[4];
  const float* wih1b = (const float*)d_in[5];
  const float* whh1b = (const float*)d_in[6];
  const float* bih1b = (const float*)d_in[7];
  const float* bhh1b = (const float*)d_in[8];
  const float* wih2f = (const float*)d_in[9];
  const float* whh2f = (const float*)d_in[10];
  const float* bih2f = (const float*)d_in[11];
  const float* bhh2f = (const float*)d_in[12];
  const float* wih2b = (const float*)d_in[13];
  const float* whh2b = (const float*)d_in[14];
  const float* bih2b = (const float*)d_in[15];
  const float* bhh2b = (const float*)d_in[16];
  const float* wih3  = (const float*)d_in[17];
  const float* whh3  = (const float*)d_in[18];
  const float* bih3  = (const float*)d_in[19];
  const float* bhh3  = (const float*)d_in[20];

  using usp = unsigned short*;
  const size_t PL = (size_t)BATCH * T * 16;  // ushorts per plane (padded 16ch)
  usp y1fh = (usp)d_ws;
  usp y1fl = y1fh + PL;
  usp y1bh = y1fl + PL;
  usp y1bl = y1bh + PL;
  usp y2fh = y1bl + PL;
  usp y2fl = y2fh + PL;
  usp y2bh = y2fl + PL;
  usp y2bl = y2bh + PL;
  float* out = (float*)d_out;

  const dim3 blk(256);
  const dim3 grid_bi(BATCH / 64, 2);
  const dim3 grid_uni(BATCH / 64, 1);

  lstm_k<0, 0><<<grid_bi, blk, 0, stream>>>(
      x, nullptr, nullptr, nullptr, nullptr,
      wih1f, whh1f, bih1f, bhh1f, wih1b, whh1b, bih1b, bhh1b,
      y1fh, y1fl, y1bh, y1bl, nullptr);
  lstm_k<1, 0><<<grid_bi, blk, 0, stream>>>(
      nullptr, y1fh, y1fl, y1bh, y1bl,
      wih2f, whh2f, bih2f, bhh2f, wih2b, whh2b, bih2b, bhh2b,
      y2fh, y2fl, y2bh, y2bl, nullptr);
  lstm_k<1, 1><<<grid_uni, blk, 0, stream>>>(
      nullptr, y2fh, y2fl, y2bh, y2bl,
      wih3, whh3, bih3, bhh3, wih3, whh3, bih3, bhh3,
      nullptr, nullptr, nullptr, nullptr, out);
}

// Round 9
// 330.440 us; speedup vs baseline: 1.4204x; 1.0290x over previous
//
#include <hip/hip_runtime.h>

#define DEV __device__ __forceinline__

typedef short bf16x8 __attribute__((ext_vector_type(8)));
typedef float f32x4 __attribute__((ext_vector_type(4)));

constexpr int BATCH = 16384, T = 64, H = 14;
constexpr float NL2E  = -1.4426950408889634f;   // -log2(e)
constexpr float N2L2E = -2.8853900817779268f;   // -2*log2(e)

union FragU { bf16x8 v; unsigned u[4]; };

DEV unsigned cvtpk(float lo, float hi) {
  unsigned r;
  asm("v_cvt_pk_bf16_f32 %0, %1, %2" : "=v"(r) : "v"(lo), "v"(hi));
  return r;
}
DEV float pklo(unsigned u) { return __uint_as_float(u << 16); }
DEV float pkhi(unsigned u) { return __uint_as_float(u & 0xffff0000u); }

DEV f32x4 MFMA(FragU a, FragU b, f32x4 c) {
  return __builtin_amdgcn_mfma_f32_16x16x32_bf16(a.v, b.v, c, 0, 0, 0);
}

// One LSTM layer; one direction per blockIdx.y; one wave = SEQPW sequences
// (SEQPW=8 duplicates A rows 8-15 -> 2x waves, used for the grid-starved
// uni layer). Inter-layer tensors: per-direction bf16 hi/lo planes
// [seq][t][16ch] (32B rows); y staged in LDS, flushed every 8 steps as
// full-line bursts. h in LDS as 3 bf16 component planes; hc1 slots 14,15
// fixed at 1.0 -> bias rides in B there. Weights pre-scaled by -log2e
// (-2log2e for g). x-side MFMAs are SOFTWARE-PIPELINED one step ahead:
// STEP(t) computes ax(t+1) while t's h-chain is in flight, so the serial
// recurrence is only ds_read -> 3 MFMA -> act -> split -> ds_write.
// INM: 0 = fp32 x [seq][t][13] (layer1) ; 1 = bf16 4-plane x (layers 2,3)
// OUTM: 0 = bf16 4-plane y ; 1 = fp32 y [seq][t][14] (layer 3)
template <int INM, int OUTM, int SEQPW>
__global__ __launch_bounds__(256, 2) void lstm_k(
    const float* __restrict__ xf,
    const unsigned short* __restrict__ xfh, const unsigned short* __restrict__ xfl,
    const unsigned short* __restrict__ xbh, const unsigned short* __restrict__ xbl,
    const float* __restrict__ wihF, const float* __restrict__ whhF,
    const float* __restrict__ bihF, const float* __restrict__ bhhF,
    const float* __restrict__ wihB, const float* __restrict__ whhB,
    const float* __restrict__ bihB, const float* __restrict__ bhhB,
    unsigned short* __restrict__ yFh, unsigned short* __restrict__ yFl,
    unsigned short* __restrict__ yBh, unsigned short* __restrict__ yBl,
    float* __restrict__ yf)
{
  constexpr int IN = (INM == 0) ? 13 : 28;
  const int dir = (OUTM == 1) ? 0 : blockIdx.y;
  const float* __restrict__ wih = dir ? wihB : wihF;
  const float* __restrict__ whh = dir ? whhB : whhF;
  const float* __restrict__ bih = dir ? bihB : bihF;
  const float* __restrict__ bhh = dir ? bhhB : bhhF;
  unsigned short* __restrict__ yhiP = dir ? yBh : yFh;
  unsigned short* __restrict__ yloP = dir ? yBl : yFl;

  const int tid = threadIdx.x;
  const int w = tid >> 6, lane = tid & 63;
  const int col = lane & 15, q = lane >> 4;
  const int qodd = q & 1, qhi = q >> 1;
  const int scol = col & (SEQPW - 1);   // A-side seq within wave
  const bool jv = col < H;
  const int jc = jv ? col : 13;

  // per (wave, seq): hc1[8] | hc2[8] | hc3[8] | pad[4] dwords (stride 28)
  __shared__ unsigned hlds[4][SEQPW][28];
  __shared__ __align__(16) unsigned short
      yst[OUTM == 0 ? 4 : 1][2][OUTM == 0 ? 8 : 1][16][16];
  __shared__ __align__(16) float fst_s[OUTM == 1 ? 4 * 8 * 8 * 14 : 4];
  float* __restrict__ fstw = fst_s + ((OUTM == 1) ? w * 896 : 0);
  {
    unsigned* hb = &hlds[w][0][0];
    for (int i = lane; i < SEQPW * 28; i += 64)
      hb[i] = ((i % 28) == 7) ? 0x3F803F80u : 0u;
  }

  // ---------------- B fragments (built once, pre-scaled) ----------------
  FragU Bx1[4], Bx2[4], Bh1[4], Bh2[4], Bh3[4];
#pragma unroll
  for (int g = 0; g < 4; ++g) {
    const int grow = g * H + jc;
    const float sc = (g == 2) ? N2L2E : NL2E;
    const float bsc = (bih[grow] + bhh[grow]) * sc;
    const unsigned bq1 = cvtpk(bsc, bsc);
    const float br1 = bsc - pklo(bq1);
    const unsigned bq2 = cvtpk(br1, br1);
    const float br2 = br1 - pklo(bq2);
    const unsigned bP12 = cvtpk(bsc, br1);   // (b1, b2)
    const unsigned bP30 = cvtpk(br2, 0.f);   // (b3, 0)
    const float* __restrict__ wr = wih + grow * IN;
    const float* __restrict__ ur = whh + grow * H;
#pragma unroll
    for (int p = 0; p < 4; ++p) {
      {  // x weights
        float wa = 0.f, wb = 0.f;
        const int l0 = 8 * qodd + 2 * p;
        if (INM == 0) {  // 13 ch; sec0 = values, sec1 = residual components
          if (jv && l0 < 13) wa = wr[l0] * sc;
          if (jv && l0 + 1 < 13) wb = wr[l0 + 1] * sc;
        } else {         // plane-local ch l; wih col = qhi*14 + l
          if (jv && l0 < 14) wa = wr[qhi * 14 + l0] * sc;
          if (jv && l0 + 1 < 14) wb = wr[qhi * 14 + l0 + 1] * sc;
        }
        const unsigned c1 = cvtpk(wa, wb);
        const float ra = wa - pklo(c1), rb = wb - pkhi(c1);
        const unsigned c2 = cvtpk(ra, rb);
        Bx1[g].u[p] = c1;
        Bx2[g].u[p] = (INM == 0 && qhi) ? 0u : c2;  // L1: sec1 of Bx2 = 0
      }
      {  // h weights: Bh1=[U1|U1](+b1,b2), Bh2=[U2|U2](+b3), Bh3=[U3|U1]
        const int m0 = 8 * qodd + 2 * p;
        const float ua = (jv && m0 < 14) ? ur[m0] * sc : 0.f;
        const float ub = (jv && (m0 + 1) < 14) ? ur[m0 + 1] * sc : 0.f;
        const unsigned c1 = cvtpk(ua, ub);
        const float ra = ua - pklo(c1), rb = ub - pkhi(c1);
        const unsigned c2 = cvtpk(ra, rb);
        const float ra2 = ra - pklo(c2), rb2 = rb - pkhi(c2);
        const unsigned c3 = cvtpk(ra2, rb2);
        unsigned h1 = c1, h2 = c2, h3 = qhi ? c1 : c3;
        if (q == 1 && p == 3) {  // sec0 slots 14,15: bias carriers (A = 1.0)
          h1 = jv ? bP12 : 0u; h2 = jv ? bP30 : 0u; h3 = 0u;
        }
        Bh1[g].u[p] = h1; Bh2[g].u[p] = h2; Bh3[g].u[p] = h3;
      }
    }
  }

  const unsigned sb = (unsigned)blockIdx.x * (4u * SEQPW) + (unsigned)w * SEQPW;
  const unsigned arow = sb + (unsigned)scol;  // this lane's seq for the A side

  // static LDS read pointers (A12: hc1/hc2 ; A13: hc1/hc3)
  const unsigned hbase = (unsigned)((w * SEQPW + scol) * 28);
  const uint4* __restrict__ rp12 =
      (const uint4*)(&hlds[0][0][0] + hbase + (qhi ? 8 : 0) + qodd * 4);
  const uint4* __restrict__ rp13 =
      (const uint4*)(&hlds[0][0][0] + hbase + (qhi ? 16 : 0) + qodd * 4);

  // static LDS write pointers for h (owner lanes only)
  const bool owner = (SEQPW == 16) || (q < 2);
  unsigned short* hw[4];
#pragma unroll
  for (int i = 0; i < 4; ++i)
    hw[i] = (unsigned short*)(&hlds[w][(SEQPW == 16 ? 4 * q : 4 * (q & 1)) + i][0]) + col;

  const int t0 = dir ? T - 1 : 0;
  const int dsx = (INM == 0) ? (dir ? -52 : 52) : (dir ? -32 : 32);
  unsigned voff0;
  if constexpr (INM == 0)
    voff0 = (arow * 64u + (unsigned)t0) * 52u + (unsigned)(qodd * 32);
  else
    voff0 = (arow * 64u + (unsigned)t0) * 32u + (unsigned)(qodd * 16);
  const unsigned short* __restrict__ xph = (INM == 0) ? nullptr : (qhi ? xbh : xfh);
  const unsigned short* __restrict__ xpl = (INM == 0) ? nullptr : (qhi ? xbl : xfl);

  float cc[4] = {0.f, 0.f, 0.f, 0.f};

  auto loadf = [&](float (&dst)[8], unsigned off) {
    const float* pa = (const float*)((const char*)xf + off);
    if (!qodd) {
#pragma unroll
      for (int e = 0; e < 8; ++e) dst[e] = pa[e];
    } else {  // l = 8..12 valid; clamp tail (B-side zeros kill the clones)
#pragma unroll
      for (int e = 0; e < 5; ++e) dst[e] = pa[e];
      dst[5] = dst[6] = dst[7] = dst[4];
    }
  };
  auto loadu = [&](unsigned (&dst)[8], unsigned off) {
    const uint4 a = *(const uint4*)((const char*)xph + off);
    const uint4 b = *(const uint4*)((const char*)xpl + off);
    dst[0] = a.x; dst[1] = a.y; dst[2] = a.z; dst[3] = a.w;
    dst[4] = b.x; dst[5] = b.y; dst[6] = b.z; dst[7] = b.w;
  };
  auto LOADX = [&](float (&df)[8], unsigned (&du)[8], unsigned off) {
    if constexpr (INM == 0) loadf(df, off); else loadu(du, off);
  };

  // x-side MFMA block (independent of h) -> ax[4]
  auto XCALC = [&](float (&xfb)[8], unsigned (&xub)[8], f32x4 (&ax)[4]) {
    FragU Ax1, Ax2;
    if constexpr (INM == 0) {
      unsigned c[4];
#pragma unroll
      for (int p = 0; p < 4; ++p) c[p] = cvtpk(xfb[2 * p], xfb[2 * p + 1]);
      if (qhi) {  // sec1 lanes carry the residual component
#pragma unroll
        for (int p = 0; p < 4; ++p) {
          const float ra = xfb[2 * p] - pklo(c[p]);
          const float rb = xfb[2 * p + 1] - pkhi(c[p]);
          c[p] = cvtpk(ra, rb);
        }
      }
#pragma unroll
      for (int p = 0; p < 4; ++p) Ax1.u[p] = c[p];
    } else {
#pragma unroll
      for (int p = 0; p < 4; ++p) { Ax1.u[p] = xub[p]; Ax2.u[p] = xub[4 + p]; }
    }
#pragma unroll
    for (int g = 0; g < 4; ++g) {
      f32x4 a = {0.f, 0.f, 0.f, 0.f};
      a = MFMA(Ax1, Bx1[g], a);          // x1W1 (+x2W1 for L1)
      if constexpr (INM == 0) {
        a = MFMA(Ax1, Bx2[g], a);        // x1W2
      } else {
        a = MFMA(Ax2, Bx1[g], a);        // x2W1
        a = MFMA(Ax1, Bx2[g], a);        // x1W2
      }
      ax[g] = a;
    }
  };

  f32x4 axC[4];  // x-contribution for the CURRENT step (pipelined)

  auto STEP = [&](int t, float (&nf)[8], unsigned (&nu)[8]) {
    // 1. h fragments (issue reads first; wait lands at first h-MFMA use)
    FragU A12, A13;
    { const uint4 t4 = *rp12; A12.u[0]=t4.x; A12.u[1]=t4.y; A12.u[2]=t4.z; A12.u[3]=t4.w; }
    { const uint4 t4 = *rp13; A13.u[0]=t4.x; A13.u[1]=t4.y; A13.u[2]=t4.z; A13.u[3]=t4.w; }
    // 2. NEXT step's x block (independent -> fills the ds_read shadow)
    f32x4 axN[4];
    XCALC(nf, nu, axN);
    // 3. h-chain MFMAs
    f32x4 ah[4];
#pragma unroll
    for (int g = 0; g < 4; ++g) {
      f32x4 a = {0.f, 0.f, 0.f, 0.f};
      a = MFMA(A12, Bh1[g], a);          // h1U1 + h2U1 + b1 + b2
      a = MFMA(A12, Bh2[g], a);          // h1U2 + h2U2 + b3
      a = MFMA(A13, Bh3[g], a);          // h1U3 + h3U1
      ah[g] = a;
    }
    // 4. activations: z' = -log2e*z (g: -2log2e*z); single-rcp cell update
    const int ts = t & 7;
#pragma unroll
    for (int i = 0; i < 4; ++i) {
      const float zi = axC[0][i] + ah[0][i];
      const float zf = axC[1][i] + ah[1][i];
      const float zg = axC[2][i] + ah[2][i];
      const float zo = axC[3][i] + ah[3][i];
      const float Ei = __builtin_amdgcn_exp2f(zi);
      const float Ef = __builtin_amdgcn_exp2f(zf);
      const float Eo = __builtin_amdgcn_exp2f(zo);
      const float Eg = __builtin_amdgcn_exp2f(-fabsf(zg));
      const float Pig = (1.f + Ei) * (1.f + Eg);
      const float F = 1.f + Ef;
      const float t2 = (1.f - Eg) * F;
      const float t2s =
          copysignf(t2, __uint_as_float(__float_as_uint(zg) ^ 0x80000000u));
      const float cn = fmaf(cc[i], Pig, t2s) * __builtin_amdgcn_rcpf(F * Pig);
      cc[i] = cn;
      const float Ec = __builtin_amdgcn_exp2f(fabsf(cn) * N2L2E);
      float hn = (1.f - Ec) * __builtin_amdgcn_rcpf((1.f + Eo) * (1.f + Ec));
      hn = copysignf(hn, cn);
      // 3-way split of h -> bf16 components
      const unsigned c1 = cvtpk(hn, hn);
      const float r1 = hn - pklo(c1);
      const unsigned c2 = cvtpk(r1, r1);
      const float r2 = r1 - pklo(c2);
      const unsigned c3 = cvtpk(r2, r2);
      if (jv && owner) {
        hw[i][0]  = (unsigned short)c1;
        hw[i][16] = (unsigned short)c2;
        hw[i][32] = (unsigned short)c3;
        if constexpr (OUTM == 0) {
          yst[w][0][ts][4 * q + i][col] = (unsigned short)c1;
          yst[w][1][ts][4 * q + i][col] = (unsigned short)c2;
        } else {
          fstw[(4 * (q & 1) + i) * 112 + ts * 14 + col] = hn;
        }
      } else if (OUTM == 0 && !jv) {  // zero pad channels (MFMA 0*NaN guard)
        yst[w][0][ts][4 * q + i][col] = 0;
        yst[w][1][ts][4 * q + i][col] = 0;
      }
    }
    // 5. rotate pipelined x-contribution
#pragma unroll
    for (int g = 0; g < 4; ++g) axC[g] = axN[g];
  };

  auto flushY = [&](int tbase) {  // 8t x 16ch x 2B = 256B/seq/plane, full lines
    const int sq = lane >> 2, part = lane & 3;
    const unsigned rowb = (sb + (unsigned)sq) * 64u + (unsigned)tbase;
#pragma unroll
    for (int pl = 0; pl < 2; ++pl) {
      char* gp0 = (char*)(pl ? yloP : yhiP);
#pragma unroll
      for (int r = 0; r < 2; ++r) {
        const int tt = 2 * part + r;
        const uint4 v0 = *(const uint4*)&yst[w][pl][tt][sq][0];
        const uint4 v1 = *(const uint4*)&yst[w][pl][tt][sq][8];
        char* gp = gp0 + (rowb + (unsigned)tt) * 32u;
        *(uint4*)(gp) = v0;
        *(uint4*)(gp + 16) = v1;
      }
    }
  };
  auto flushO = [&](int tbase) {  // 8t x 14f = 448B/seq contiguous
    const int sq = lane >> 3, part = lane & 7;
    char* gp = (char*)yf + ((sb + (unsigned)sq) * 64u + (unsigned)tbase) * 56u;
    const float* src = fstw + sq * 112 + part;
#pragma unroll
    for (int m = 0; m < 14; ++m)
      *(float*)(gp + (part + 8 * m) * 4) = src[8 * m];
  };

  auto tj = [&](int j) { return dir ? T - 1 - j : j; };

  float fA[8], fB[8], fC[8], fD[8];
  unsigned uA[8], uB[8], uC[8], uD[8];
  const unsigned vA0 = voff0, vB0 = voff0 + (unsigned)dsx;
  LOADX(fA, uA, vA0);
  LOADX(fB, uB, vB0);
  XCALC(fA, uA, axC);   // ax for step t0
  unsigned vLast = vB0;
#pragma unroll 1
  for (int s = 0; s < T; s += 4) {
    const unsigned vC = vLast + (unsigned)dsx;
    const unsigned vD = vC + (unsigned)dsx;
    LOADX(fC, uC, vC);
    LOADX(fD, uD, vD);
    STEP(tj(s), fB, uB);       // consumes axC(t=s); builds ax(t=s+1) from B
    STEP(tj(s + 1), fC, uC);
    unsigned vE = vD;
    if (s + 4 < T) {
      const unsigned vA2 = vD + (unsigned)dsx;
      const unsigned vB2 = vA2 + (unsigned)dsx;
      LOADX(fA, uA, vA2);
      LOADX(fB, uB, vB2);
      vE = vB2;
    }
    STEP(tj(s + 2), fD, uD);
    STEP(tj(s + 3), fA, uA);   // at tail, fA is stale -> axN dead, harmless
    vLast = vE;
    if ((s & 7) == 4) {
      const int tbase = dir ? (T - 8 - (s - 4)) : (s - 4);
      if constexpr (OUTM == 0) flushY(tbase); else flushO(tbase);
    }
  }
}

extern "C" void kernel_launch(void* const* d_in, const int* in_sizes, int n_in,
                              void* d_out, int out_size, void* d_ws, size_t ws_size,
                              hipStream_t stream) {
  const float* x     = (const float*)d_in[0];
  const float* wih1f = (const float*)d_in[1];
  const float* whh1f = (const float*)d_in[2];
  const float* bih1f = (const float*)d_in[3];
  const float* bhh1f = (const float*)d_in[4];
  const float* wih1b = (const float*)d_in[5];
  const float* whh1b = (const float*)d_in[6];
  const float* bih1b = (const float*)d_in[7];
  const float* bhh1b = (const float*)d_in[8];
  const float* wih2f = (const float*)d_in[9];
  const float* whh2f = (const float*)d_in[10];
  const float* bih2f = (const float*)d_in[11];
  const float* bhh2f = (const float*)d_in[12];
  const float* wih2b = (const float*)d_in[13];
  const float* whh2b = (const float*)d_in[14];
  const float* bih2b = (const float*)d_in[15];
  const float* bhh2b = (const float*)d_in[16];
  const float* wih3  = (const float*)d_in[17];
  const float* whh3  = (const float*)d_in[18];
  const float* bih3  = (const float*)d_in[19];
  const float* bhh3  = (const float*)d_in[20];

  using usp = unsigned short*;
  const size_t PL = (size_t)BATCH * T * 16;  // ushorts per plane (padded 16ch)
  usp y1fh = (usp)d_ws;
  usp y1fl = y1fh + PL;
  usp y1bh = y1fl + PL;
  usp y1bl = y1bh + PL;
  usp y2fh = y1bl + PL;
  usp y2fl = y2fh + PL;
  usp y2bh = y2fl + PL;
  usp y2bl = y2bh + PL;
  float* out = (float*)d_out;

  const dim3 blk(256);
  const dim3 grid_bi(BATCH / 64, 2);
  const dim3 grid_uni(BATCH / 32, 1);   // 8-seq tiles -> 2 waves/SIMD

  lstm_k<0, 0, 16><<<grid_bi, blk, 0, stream>>>(
      x, nullptr, nullptr, nullptr, nullptr,
      wih1f, whh1f, bih1f, bhh1f, wih1b, whh1b, bih1b, bhh1b,
      y1fh, y1fl, y1bh, y1bl, nullptr);
  lstm_k<1, 0, 16><<<grid_bi, blk, 0, stream>>>(
      nullptr, y1fh, y1fl, y1bh, y1bl,
      wih2f, whh2f, bih2f, bhh2f, wih2b, whh2b, bih2b, bhh2b,
      y2fh, y2fl, y2bh, y2bl, nullptr);
  lstm_k<1, 1, 8><<<grid_uni, blk, 0, stream>>>(
      nullptr, y2fh, y2fl, y2bh, y2bl,
      wih3, whh3, bih3, bhh3, wih3, whh3, bih3, bhh3,
      nullptr, nullptr, nullptr, nullptr, out);
}

// Round 11
// 299.282 us; speedup vs baseline: 1.5682x; 1.1041x over previous
//
#include <hip/hip_runtime.h>

#define DEV __device__ __forceinline__

typedef short bf16x8 __attribute__((ext_vector_type(8)));
typedef float f32x4 __attribute__((ext_vector_type(4)));

constexpr int BATCH = 16384, T = 64, H = 14;
constexpr float NL2E  = -1.4426950408889634f;   // -log2(e)
constexpr float N2L2E = -2.8853900817779268f;   // -2*log2(e)

union FragU { bf16x8 v; unsigned u[4]; };

template <int N> struct icx { static constexpr int value = N; };

DEV unsigned cvtpk(float lo, float hi) {
  unsigned r;
  asm("v_cvt_pk_bf16_f32 %0, %1, %2" : "=v"(r) : "v"(lo), "v"(hi));
  return r;
}
DEV float pklo(unsigned u) { return __uint_as_float(u << 16); }
DEV float pkhi(unsigned u) { return __uint_as_float(u & 0xffff0000u); }

DEV f32x4 MFMA(FragU a, FragU b, f32x4 c) {
  return __builtin_amdgcn_mfma_f32_16x16x32_bf16(a.v, b.v, c, 0, 0, 0);
}
// chain head: D = A*B + C0 into a FRESH dest (no accumulator zero-init movs).
// s_nop 1 covers the VALU-write -> MFMA-read hazard the compiler can't see.
DEV f32x4 MFMA_first(bf16x8 a, bf16x8 b, f32x4 c0) {
  f32x4 d;
  asm("s_nop 1\n\tv_mfma_f32_16x16x32_bf16 %0, %1, %2, %3"
      : "=&v"(d) : "v"(a), "v"(b), "v"(c0));
  return d;
}

// One LSTM layer; one direction per blockIdx.y; one wave = SEQPW sequences.
// h lives in an 8-slot LDS ring of bf16 hi/lo component planes; the ring IS
// the y staging buffer (flushed to global hi/lo planes every 8 steps as full
// 64B lines). Channels 14/15 of every ring row are zeroed at init and never
// written afterwards (0 x 0 = 0 in MFMA; NaN guard). Bias enters as the MFMA
// C-operand (exact fp32, built once). Weights/bias pre-scaled by -log2e
// (-2log2e for g gate) -> activations use exp2 directly. x-side MFMAs
// software-pipelined one step ahead; 8-step unrolled loop makes every LDS
// address a compile-time immediate.
// INM: 0 = fp32 x [seq][t][13] (layer1) ; 1 = bf16 4-plane x (layers 2,3)
// OUTM: 0 = bf16 4-plane y ; 1 = fp32 y [seq][t][14] (layer 3, SEQPW=8)
template <int INM, int OUTM, int SEQPW>
__global__ __launch_bounds__(256, 2) void lstm_k(
    const float* __restrict__ xf,
    const unsigned short* __restrict__ xfh, const unsigned short* __restrict__ xfl,
    const unsigned short* __restrict__ xbh, const unsigned short* __restrict__ xbl,
    const float* __restrict__ wihF, const float* __restrict__ whhF,
    const float* __restrict__ bihF, const float* __restrict__ bhhF,
    const float* __restrict__ wihB, const float* __restrict__ whhB,
    const float* __restrict__ bihB, const float* __restrict__ bhhB,
    unsigned short* __restrict__ yFh, unsigned short* __restrict__ yFl,
    unsigned short* __restrict__ yBh, unsigned short* __restrict__ yBl,
    float* __restrict__ yf)
{
  constexpr int IN = (INM == 0) ? 13 : 28;
  const int dir = (OUTM == 1) ? 0 : blockIdx.y;
  const float* __restrict__ wih = dir ? wihB : wihF;
  const float* __restrict__ whh = dir ? whhB : whhF;
  const float* __restrict__ bih = dir ? bihB : bihF;
  const float* __restrict__ bhh = dir ? bhhB : bhhF;
  unsigned short* __restrict__ yhiP = dir ? yBh : yFh;
  unsigned short* __restrict__ yloP = dir ? yBl : yFl;

  const int tid = threadIdx.x;
  const int w = tid >> 6, lane = tid & 63;
  const int col = lane & 15, q = lane >> 4;
  const int qodd = q & 1, qhi = q >> 1;
  const int scol = col & (SEQPW - 1);
  const bool jv = col < H;
  const int jc = jv ? col : 13;
  const int qe = (SEQPW == 16) ? q : (q & 1);
  const bool owner = (SEQPW == 16) || (q < 2);

  // ring: [wave][slot 0..7][seq][ hc1 dw0..7 | hc2 dw8..15 | pad dw16..19 ]
  __shared__ unsigned ringS[4][8][SEQPW][20];
  __shared__ __align__(16) float fst_s[OUTM == 1 ? 4 * 8 * 8 * 14 : 4];
  unsigned* const ringD = &ringS[0][0][0][0];
  unsigned short* const ringU = (unsigned short*)ringD;
  float* const fstw = fst_s + ((OUTM == 1) ? w * 896 : 0);

  {  // zero the WHOLE per-wave ring: slot 7 is step-0's h=0 input, and ring
     // channels 14/15 (never written later) must be 0, not LDS garbage --
     // they feed MFMAs against zero B-columns (0 x NaN = NaN otherwise) and
     // are flushed into the y planes read by the next layer.
    unsigned* rz = ringD + (unsigned)(w * 8 * SEQPW) * 20u;
    for (int i = lane; i < 8 * SEQPW * 20; i += 64) rz[i] = 0u;
  }

  // ---------------- B fragments + fp32 bias C0 (built once) ----------------
  FragU Bx1[4], Bx2[4], Bh1[4], Bh2[4];
  f32x4 bbq[4];
#pragma unroll
  for (int g = 0; g < 4; ++g) {
    const int grow = g * H + jc;
    const float sc = (g == 2) ? N2L2E : NL2E;
    const float bsc = jv ? (bih[grow] + bhh[grow]) * sc : 0.f;
    bbq[g] = (f32x4){bsc, bsc, bsc, bsc};
    const float* __restrict__ wr = wih + grow * IN;
    const float* __restrict__ ur = whh + grow * H;
#pragma unroll
    for (int p = 0; p < 4; ++p) {
      {  // x weights (2 components)
        float wa = 0.f, wb = 0.f;
        const int l0 = 8 * qodd + 2 * p;
        if (INM == 0) {  // 13 ch; sec0 = values, sec1 = residuals
          if (jv && l0 < 13) wa = wr[l0] * sc;
          if (jv && l0 + 1 < 13) wb = wr[l0 + 1] * sc;
        } else {         // plane-local ch; wih col = qhi*14 + l
          if (jv && l0 < 14) wa = wr[qhi * 14 + l0] * sc;
          if (jv && l0 + 1 < 14) wb = wr[qhi * 14 + l0 + 1] * sc;
        }
        const unsigned c1 = cvtpk(wa, wb);
        const float ra = wa - pklo(c1), rb = wb - pkhi(c1);
        const unsigned c2 = cvtpk(ra, rb);
        Bx1[g].u[p] = c1;
        Bx2[g].u[p] = (INM == 0 && qhi) ? 0u : c2;  // L1: sec1 of Bx2 = 0
      }
      {  // h weights (2 components): Bh1=[U1|U1], Bh2=[U2|U2]
        const int m0 = 8 * qodd + 2 * p;
        const float ua = (jv && m0 < 14) ? ur[m0] * sc : 0.f;
        const float ub = (jv && (m0 + 1) < 14) ? ur[m0 + 1] * sc : 0.f;
        const unsigned c1 = cvtpk(ua, ub);
        const float ra = ua - pklo(c1), rb = ub - pkhi(c1);
        const unsigned c2 = cvtpk(ra, rb);
        Bh1[g].u[p] = c1;
        Bh2[g].u[p] = c2;
      }
    }
  }

  const unsigned sb = (unsigned)blockIdx.x * (4u * SEQPW) + (unsigned)w * SEQPW;
  const unsigned arow = sb + (unsigned)scol;

  // LDS bases (all per-step addresses = base + compile-time immediate)
  const unsigned rdBase = ((unsigned)(w * 8) * SEQPW + (unsigned)scol) * 20u +
                          (unsigned)(qhi * 8 + qodd * 4);
  const unsigned wrBase =
      ((unsigned)(w * 8) * SEQPW + (unsigned)(4 * qe)) * 40u + (unsigned)col;

  const int t0 = dir ? T - 1 : 0;
  const int dsx = (INM == 0) ? (dir ? -52 : 52) : (dir ? -32 : 32);
  int voff0;
  if constexpr (INM == 0)
    voff0 = (int)((arow * 64u + (unsigned)t0) * 52u) + qodd * 32;
  else
    voff0 = (int)((arow * 64u + (unsigned)t0) * 32u) + qodd * 16;
  const unsigned short* __restrict__ xph = (INM == 0) ? nullptr : (qhi ? xbh : xfh);
  const unsigned short* __restrict__ xpl = (INM == 0) ? nullptr : (qhi ? xbl : xfl);

  float cc[4] = {0.f, 0.f, 0.f, 0.f};

  auto loadf = [&](float (&dst)[8], int off) {
    const float* pa = (const float*)((const char*)xf + off);
    if (!qodd) {
#pragma unroll
      for (int e = 0; e < 8; ++e) dst[e] = pa[e];
    } else {  // l = 8..12 valid; clamp tail (B-side zeros kill the clones)
#pragma unroll
      for (int e = 0; e < 5; ++e) dst[e] = pa[e];
      dst[5] = dst[6] = dst[7] = dst[4];
    }
  };
  auto loadu = [&](unsigned (&dst)[8], int off) {
    const uint4 a = *(const uint4*)((const char*)xph + off);
    const uint4 b = *(const uint4*)((const char*)xpl + off);
    dst[0] = a.x; dst[1] = a.y; dst[2] = a.z; dst[3] = a.w;
    dst[4] = b.x; dst[5] = b.y; dst[6] = b.z; dst[7] = b.w;
  };
  auto LOADX = [&](float (&df)[8], unsigned (&du)[8], int off) {
    if constexpr (INM == 0) loadf(df, off); else loadu(du, off);
  };

  // x-side MFMA block (independent of h): ax = bias + x*Wih^T
  auto XCALC = [&](float (&xfb)[8], unsigned (&xub)[8], f32x4 (&ax)[4]) {
    FragU Ax1, Ax2;
    if constexpr (INM == 0) {
      unsigned c[4];
#pragma unroll
      for (int p = 0; p < 4; ++p) c[p] = cvtpk(xfb[2 * p], xfb[2 * p + 1]);
      if (qhi) {  // sec1 lanes carry the residual component
#pragma unroll
        for (int p = 0; p < 4; ++p) {
          const float ra = xfb[2 * p] - pklo(c[p]);
          const float rb = xfb[2 * p + 1] - pkhi(c[p]);
          c[p] = cvtpk(ra, rb);
        }
      }
#pragma unroll
      for (int p = 0; p < 4; ++p) Ax1.u[p] = c[p];
    } else {
#pragma unroll
      for (int p = 0; p < 4; ++p) { Ax1.u[p] = xub[p]; Ax2.u[p] = xub[4 + p]; }
    }
#pragma unroll
    for (int g = 0; g < 4; ++g) {
      f32x4 a = MFMA_first(Ax1.v, Bx1[g].v, bbq[g]);  // bias + x1W1 (+x2W1 L1)
      if constexpr (INM == 0) {
        a = MFMA(Ax1, Bx2[g], a);                     // x1W2
      } else {
        a = MFMA(Ax2, Bx1[g], a);                     // x2W1
        a = MFMA(Ax1, Bx2[g], a);                     // x1W2
      }
      ax[g] = a;
    }
  };

  // One recurrent step. J = compile-time slot index (step s+J, s%8==0).
  auto STEP = [&](auto Jc, float (&nf)[8], unsigned (&nu)[8],
                  f32x4 (&cur)[4], f32x4 (&nxt)[4]) {
    constexpr int J = decltype(Jc)::value;
    constexpr int SLOT_R = (J + 7) & 7;
    // 1. h fragment from ring (single b128; static slot offset)
    FragU A12;
    {
      const uint4 t4 =
          *(const uint4*)(ringD + rdBase + (unsigned)(SLOT_R * SEQPW * 20));
      A12.u[0] = t4.x; A12.u[1] = t4.y; A12.u[2] = t4.z; A12.u[3] = t4.w;
    }
    // 2. next step's x block (fills the ds_read shadow)
    XCALC(nf, nu, nxt);
    // 3. h-chain (depth 2) accumulated onto the pipelined x result
    f32x4 z[4];
#pragma unroll
    for (int g = 0; g < 4; ++g)
      z[g] = MFMA(A12, Bh2[g], MFMA(A12, Bh1[g], cur[g]));
    // 4. activations (pre-scaled: z' = -log2e*z ; g: -2log2e*z)
#pragma unroll
    for (int i = 0; i < 4; ++i) {
      const float zi = z[0][i], zf = z[1][i], zg = z[2][i], zo = z[3][i];
      const float Ei = __builtin_amdgcn_exp2f(zi);
      const float Ef = __builtin_amdgcn_exp2f(zf);
      const float Eo = __builtin_amdgcn_exp2f(zo);
      const float Eg = __builtin_amdgcn_exp2f(-fabsf(zg));
      const float Pig = (1.f + Ei) * (1.f + Eg);
      const float F = 1.f + Ef;
      const float t2 = (1.f - Eg) * F;
      const float t2s =
          copysignf(t2, __uint_as_float(__float_as_uint(zg) ^ 0x80000000u));
      const float cn = fmaf(cc[i], Pig, t2s) * __builtin_amdgcn_rcpf(F * Pig);
      cc[i] = cn;
      const float Ec = __builtin_amdgcn_exp2f(fabsf(cn) * N2L2E);
      float hn = (1.f - Ec) * __builtin_amdgcn_rcpf((1.f + Eo) * (1.f + Ec));
      hn = copysignf(hn, cn);
      const unsigned c1 = cvtpk(hn, hn);          // hi component (both halves)
      const float r1 = hn - pklo(c1);
      const unsigned c2 = cvtpk(r1, r1);          // lo component
      if (jv && owner) {
        ringU[wrBase + (unsigned)(J * SEQPW * 40 + i * 40)]      = (unsigned short)c1;
        ringU[wrBase + (unsigned)(J * SEQPW * 40 + i * 40 + 16)] = (unsigned short)c2;
        if constexpr (OUTM == 1)
          fstw[(4 * (q & 1) + i) * 112 + J * 14 + col] = hn;
      }
    }
  };

  // flush ring -> global bf16 hi/lo planes (full 64B lines)
  auto flushY8 = [&](int sBase) {
    const int sq = lane >> 2, part = lane & 3;
#pragma unroll
    for (int rr = 0; rr < 2; ++rr) {
      const int r = 2 * part + rr;  // slot = step offset within the block
      const int tg = dir ? (63 - (sBase + r)) : (sBase + r);
      const unsigned* src =
          ringD + ((unsigned)(w * 8 + r) * SEQPW + (unsigned)sq) * 20u;
      const uint4 h0 = *(const uint4*)(src);
      const uint4 h1 = *(const uint4*)(src + 4);
      const uint4 l0 = *(const uint4*)(src + 8);
      const uint4 l1 = *(const uint4*)(src + 12);
      const unsigned gb = ((sb + (unsigned)sq) * 64u + (unsigned)tg) * 32u;
      char* gph = (char*)yhiP + gb;
      char* gpl = (char*)yloP + gb;
      *(uint4*)(gph) = h0; *(uint4*)(gph + 16) = h1;
      *(uint4*)(gpl) = l0; *(uint4*)(gpl + 16) = l1;
    }
  };
  auto flushO = [&](int tbase) {  // fp32 out: 448B/seq contiguous, coalesced
    const int sq = lane >> 3, part = lane & 7;
    char* gp = (char*)yf + ((sb + (unsigned)sq) * 64u + (unsigned)tbase) * 56u;
    const float* src = fstw + sq * 112 + part;
#pragma unroll
    for (int m = 0; m < 14; ++m)
      *(float*)(gp + (part + 8 * m) * 4) = src[8 * m];
  };

  float fA[8], fB[8], fC[8], fD[8];
  unsigned uA[8], uB[8], uC[8], uD[8];
  f32x4 axP[4], axQ[4];

  LOADX(fA, uA, voff0);
  LOADX(fB, uB, voff0 + dsx);
  XCALC(fA, uA, axP);  // ax for step 0

#pragma unroll 1
  for (int s = 0; s < T; s += 8) {
    const int vb = voff0 + s * dsx;
    LOADX(fC, uC, vb + 2 * dsx);
    LOADX(fD, uD, vb + 3 * dsx);
    STEP(icx<0>{}, fB, uB, axP, axQ);
    STEP(icx<1>{}, fC, uC, axQ, axP);
    LOADX(fA, uA, vb + 4 * dsx);
    LOADX(fB, uB, vb + 5 * dsx);
    STEP(icx<2>{}, fD, uD, axP, axQ);
    STEP(icx<3>{}, fA, uA, axQ, axP);
    LOADX(fC, uC, vb + 6 * dsx);
    LOADX(fD, uD, vb + 7 * dsx);
    STEP(icx<4>{}, fB, uB, axP, axQ);
    STEP(icx<5>{}, fC, uC, axQ, axP);
    const int k8 = (s + 8 < T) ? 8 : 7;
    const int k9 = (s + 9 < T) ? 9 : 7;
    LOADX(fA, uA, vb + k8 * dsx);
    LOADX(fB, uB, vb + k9 * dsx);
    STEP(icx<6>{}, fD, uD, axP, axQ);
    STEP(icx<7>{}, fA, uA, axQ, axP);
    if constexpr (OUTM == 0) flushY8(s); else flushO(s);
  }
}

extern "C" void kernel_launch(void* const* d_in, const int* in_sizes, int n_in,
                              void* d_out, int out_size, void* d_ws, size_t ws_size,
                              hipStream_t stream) {
  const float* x     = (const float*)d_in[0];
  const float* wih1f = (const float*)d_in[1];
  const float* whh1f = (const float*)d_in[2];
  const float* bih1f = (const float*)d_in[3];
  const float* bhh1f = (const float*)d_in[4];
  const float* wih1b = (const float*)d_in[5];
  const float* whh1b = (const float*)d_in[6];
  const float* bih1b = (const float*)d_in[7];
  const float* bhh1b = (const float*)d_in[8];
  const float* wih2f = (const float*)d_in[9];
  const float* whh2f = (const float*)d_in[10];
  const float* bih2f = (const float*)d_in[11];
  const float* bhh2f = (const float*)d_in[12];
  const float* wih2b = (const float*)d_in[13];
  const float* whh2b = (const float*)d_in[14];
  const float* bih2b = (const float*)d_in[15];
  const float* bhh2b = (const float*)d_in[16];
  const float* wih3  = (const float*)d_in[17];
  const float* whh3  = (const float*)d_in[18];
  const float* bih3  = (const float*)d_in[19];
  const float* bhh3  = (const float*)d_in[20];

  using usp = unsigned short*;
  const size_t PL = (size_t)BATCH * T * 16;  // ushorts per plane (padded 16ch)
  usp y1fh = (usp)d_ws;
  usp y1fl = y1fh + PL;
  usp y1bh = y1fl + PL;
  usp y1bl = y1bh + PL;
  usp y2fh = y1bl + PL;
  usp y2fl = y2fh + PL;
  usp y2bh = y2fl + PL;
  usp y2bl = y2bh + PL;
  float* out = (float*)d_out;

  const dim3 blk(256);
  const dim3 grid_bi(BATCH / 64, 2);
  const dim3 grid_uni(BATCH / 32, 1);  // SEQPW=8 -> 2 waves/SIMD

  lstm_k<0, 0, 16><<<grid_bi, blk, 0, stream>>>(
      x, nullptr, nullptr, nullptr, nullptr,
      wih1f, whh1f, bih1f, bhh1f, wih1b, whh1b, bih1b, bhh1b,
      y1fh, y1fl, y1bh, y1bl, nullptr);
  lstm_k<1, 0, 16><<<grid_bi, blk, 0, stream>>>(
      nullptr, y1fh, y1fl, y1bh, y1bl,
      wih2f, whh2f, bih2f, bhh2f, wih2b, whh2b, bih2b, bhh2b,
      y2fh, y2fl, y2bh, y2bl, nullptr);
  lstm_k<1, 1, 8><<<grid_uni, blk, 0, stream>>>(
      nullptr, y2fh, y2fl, y2bh, y2bl,
      wih3, whh3, bih3, bhh3, wih3, whh3, bih3, bhh3,
      nullptr, nullptr, nullptr, nullptr, out);
}

// Round 12
// 247.705 us; speedup vs baseline: 1.8948x; 1.2082x over previous
//
#include <hip/hip_runtime.h>

#define DEV __device__ __forceinline__

typedef short bf16x8 __attribute__((ext_vector_type(8)));
typedef float f32x4 __attribute__((ext_vector_type(4)));

constexpr int BATCH = 16384, T = 64, H = 14;
constexpr float NL2E  = -1.4426950408889634f;   // -log2(e)
constexpr float N2L2E = -2.8853900817779268f;   // -2*log2(e)

union FragU { bf16x8 v; unsigned u[4]; };

template <int N> struct icx { static constexpr int value = N; };

DEV unsigned cvtpk(float lo, float hi) {
  unsigned r;
  asm("v_cvt_pk_bf16_f32 %0, %1, %2" : "=v"(r) : "v"(lo), "v"(hi));
  return r;
}
DEV float pklo(unsigned u) { return __uint_as_float(u << 16); }
DEV float pkhi(unsigned u) { return __uint_as_float(u & 0xffff0000u); }

DEV f32x4 MFMA(FragU a, FragU b, f32x4 c) {
  return __builtin_amdgcn_mfma_f32_16x16x32_bf16(a.v, b.v, c, 0, 0, 0);
}

// One LSTM layer; one direction per blockIdx.y; one wave = SEQPW sequences.
// h lives in an 8-slot LDS ring of bf16 hi/lo component planes; the hi half
// of the ring IS the y staging buffer (flushed to the global hi plane every
// 8 steps as full 64B lines). Inter-layer x is SINGLE-bf16 (hi plane only);
// weights keep hi+lo components and h keeps 2 components (recurrent path
// stays near-fp32). Bias enters as the MFMA C-operand. Weights/bias
// pre-scaled by -log2e (-2log2e for g). x prefetched 4-5 steps ahead via an
// 8-buffer rotation; 8-step unrolled loop -> all LDS addresses immediate.
// INM: 0 = fp32 x [seq][t][13] (layer1) ; 1 = bf16 hi-plane x (layers 2,3)
// OUTM: 0 = bf16 hi-plane y ; 1 = fp32 y [seq][t][14] (layer 3, SEQPW=8)
template <int INM, int OUTM, int SEQPW>
__global__ __launch_bounds__(256, 2) void lstm_k(
    const float* __restrict__ xf,
    const unsigned short* __restrict__ xfh,
    const unsigned short* __restrict__ xbh,
    const float* __restrict__ wihF, const float* __restrict__ whhF,
    const float* __restrict__ bihF, const float* __restrict__ bhhF,
    const float* __restrict__ wihB, const float* __restrict__ whhB,
    const float* __restrict__ bihB, const float* __restrict__ bhhB,
    unsigned short* __restrict__ yFh, unsigned short* __restrict__ yBh,
    float* __restrict__ yf)
{
  constexpr int IN = (INM == 0) ? 13 : 28;
  const int dir = (OUTM == 1) ? 0 : blockIdx.y;
  const float* __restrict__ wih = dir ? wihB : wihF;
  const float* __restrict__ whh = dir ? whhB : whhF;
  const float* __restrict__ bih = dir ? bihB : bihF;
  const float* __restrict__ bhh = dir ? bhhB : bhhF;
  unsigned short* __restrict__ yhiP = dir ? yBh : yFh;

  const int tid = threadIdx.x;
  const int w = tid >> 6, lane = tid & 63;
  const int col = lane & 15, q = lane >> 4;
  const int qodd = q & 1, qhi = q >> 1;
  const int scol = col & (SEQPW - 1);
  const bool jv = col < H;
  const int jc = jv ? col : 13;
  const int qe = (SEQPW == 16) ? q : (q & 1);
  const bool owner = (SEQPW == 16) || (q < 2);

  // ring: [wave][slot 0..7][seq][ hc1 dw0..7 | hc2 dw8..15 | pad dw16..19 ]
  __shared__ unsigned ringS[4][8][SEQPW][20];
  __shared__ __align__(16) float fst_s[OUTM == 1 ? 4 * 8 * 8 * 14 : 4];
  unsigned* const ringD = &ringS[0][0][0][0];
  unsigned short* const ringU = (unsigned short*)ringD;
  float* const fstw = fst_s + ((OUTM == 1) ? w * 896 : 0);

  {  // zero the WHOLE per-wave ring (slot 7 = step-0 h; ch 14/15 stay 0
     // forever: they feed MFMAs against zero B-cols and flush to y planes)
    unsigned* rz = ringD + (unsigned)(w * 8 * SEQPW) * 20u;
    for (int i = lane; i < 8 * SEQPW * 20; i += 64) rz[i] = 0u;
  }

  // ---------------- B fragments + fp32 bias C0 (built once) ----------------
  FragU Bx1[4], Bx2[4], Bh1[4], Bh2[4];
  f32x4 bbq[4];
#pragma unroll
  for (int g = 0; g < 4; ++g) {
    const int grow = g * H + jc;
    const float sc = (g == 2) ? N2L2E : NL2E;
    const float bsc = jv ? (bih[grow] + bhh[grow]) * sc : 0.f;
    bbq[g] = (f32x4){bsc, bsc, bsc, bsc};
    const float* __restrict__ wr = wih + grow * IN;
    const float* __restrict__ ur = whh + grow * H;
#pragma unroll
    for (int p = 0; p < 4; ++p) {
      {  // x weights (2 components kept)
        float wa = 0.f, wb = 0.f;
        const int l0 = 8 * qodd + 2 * p;
        if (INM == 0) {  // 13 ch; sec0 = values, sec1 = residuals
          if (jv && l0 < 13) wa = wr[l0] * sc;
          if (jv && l0 + 1 < 13) wb = wr[l0 + 1] * sc;
        } else {         // plane-local ch; wih col = qhi*14 + l
          if (jv && l0 < 14) wa = wr[qhi * 14 + l0] * sc;
          if (jv && l0 + 1 < 14) wb = wr[qhi * 14 + l0 + 1] * sc;
        }
        const unsigned c1 = cvtpk(wa, wb);
        const float ra = wa - pklo(c1), rb = wb - pkhi(c1);
        const unsigned c2 = cvtpk(ra, rb);
        Bx1[g].u[p] = c1;
        Bx2[g].u[p] = (INM == 0 && qhi) ? 0u : c2;  // L1: sec1 of Bx2 = 0
      }
      {  // h weights (2 components): Bh1=[U1|U1], Bh2=[U2|U2]
        const int m0 = 8 * qodd + 2 * p;
        const float ua = (jv && m0 < 14) ? ur[m0] * sc : 0.f;
        const float ub = (jv && (m0 + 1) < 14) ? ur[m0 + 1] * sc : 0.f;
        const unsigned c1 = cvtpk(ua, ub);
        const float ra = ua - pklo(c1), rb = ub - pkhi(c1);
        const unsigned c2 = cvtpk(ra, rb);
        Bh1[g].u[p] = c1;
        Bh2[g].u[p] = c2;
      }
    }
  }

  const unsigned sb = (unsigned)blockIdx.x * (4u * SEQPW) + (unsigned)w * SEQPW;
  const unsigned arow = sb + (unsigned)scol;

  // LDS bases (all per-step addresses = base + compile-time immediate)
  const unsigned rdBase = ((unsigned)(w * 8) * SEQPW + (unsigned)scol) * 20u +
                          (unsigned)(qhi * 8 + qodd * 4);
  const unsigned wrBase =
      ((unsigned)(w * 8) * SEQPW + (unsigned)(4 * qe)) * 40u + (unsigned)col;

  const int t0 = dir ? T - 1 : 0;
  const int dsx = (INM == 0) ? (dir ? -52 : 52) : (dir ? -32 : 32);
  int voff0;
  if constexpr (INM == 0)
    voff0 = (int)((arow * 64u + (unsigned)t0) * 52u) + qodd * 32;
  else
    voff0 = (int)((arow * 64u + (unsigned)t0) * 32u) + qodd * 16;
  const unsigned short* __restrict__ xph = (INM == 0) ? nullptr : (qhi ? xbh : xfh);

  float cc[4] = {0.f, 0.f, 0.f, 0.f};

  auto loadf = [&](float (&dst)[8], int off) {
    const float* pa = (const float*)((const char*)xf + off);
    if (!qodd) {
#pragma unroll
      for (int e = 0; e < 8; ++e) dst[e] = pa[e];
    } else {  // l = 8..12 valid; clamp tail (B-side zeros kill the clones)
#pragma unroll
      for (int e = 0; e < 5; ++e) dst[e] = pa[e];
      dst[5] = dst[6] = dst[7] = dst[4];
    }
  };
  auto loadu = [&](unsigned (&dst)[4], int off) {
    const uint4 a = *(const uint4*)((const char*)xph + off);
    dst[0] = a.x; dst[1] = a.y; dst[2] = a.z; dst[3] = a.w;
  };
  auto LOADX = [&](float (&df)[8], unsigned (&du)[4], int off) {
    if constexpr (INM == 0) loadf(df, off); else loadu(du, off);
  };

  // x-side MFMA block (independent of h): ax = bias + x*Wih^T
  auto XCALC = [&](float (&xfb)[8], unsigned (&xub)[4], f32x4 (&ax)[4]) {
    FragU Ax1;
    if constexpr (INM == 0) {
      unsigned c[4];
#pragma unroll
      for (int p = 0; p < 4; ++p) c[p] = cvtpk(xfb[2 * p], xfb[2 * p + 1]);
      if (qhi) {  // sec1 lanes carry the residual component
#pragma unroll
        for (int p = 0; p < 4; ++p) {
          const float ra = xfb[2 * p] - pklo(c[p]);
          const float rb = xfb[2 * p + 1] - pkhi(c[p]);
          c[p] = cvtpk(ra, rb);
        }
      }
#pragma unroll
      for (int p = 0; p < 4; ++p) Ax1.u[p] = c[p];
    } else {
#pragma unroll
      for (int p = 0; p < 4; ++p) Ax1.u[p] = xub[p];
    }
#pragma unroll
    for (int g = 0; g < 4; ++g) {
      f32x4 a = MFMA(Ax1, Bx1[g], bbq[g]);  // bias + x1W1 (+x2W1 for L1)
      a = MFMA(Ax1, Bx2[g], a);             // x1W2
      ax[g] = a;
    }
  };

  // One recurrent step. J = compile-time slot index (step s+J, s%8==0).
  auto STEP = [&](auto Jc, float (&nf)[8], unsigned (&nu)[4],
                  f32x4 (&cur)[4], f32x4 (&nxt)[4]) {
    constexpr int J = decltype(Jc)::value;
    constexpr int SLOT_R = (J + 7) & 7;
    // 1. h fragment from ring (single b128; static slot offset)
    FragU A12;
    {
      const uint4 t4 =
          *(const uint4*)(ringD + rdBase + (unsigned)(SLOT_R * SEQPW * 20));
      A12.u[0] = t4.x; A12.u[1] = t4.y; A12.u[2] = t4.z; A12.u[3] = t4.w;
    }
    // 2. next step's x block (fills the ds_read shadow)
    XCALC(nf, nu, nxt);
    // 3. h-chain (depth 2) accumulated onto the pipelined x result
    f32x4 z[4];
#pragma unroll
    for (int g = 0; g < 4; ++g)
      z[g] = MFMA(A12, Bh2[g], MFMA(A12, Bh1[g], cur[g]));
    // 4. activations (pre-scaled: z' = -log2e*z ; g: -2log2e*z)
#pragma unroll
    for (int i = 0; i < 4; ++i) {
      const float zi = z[0][i], zf = z[1][i], zg = z[2][i], zo = z[3][i];
      const float Ei = __builtin_amdgcn_exp2f(zi);
      const float Ef = __builtin_amdgcn_exp2f(zf);
      const float Eo = __builtin_amdgcn_exp2f(zo);
      const float Eg = __builtin_amdgcn_exp2f(-fabsf(zg));
      const float Pig = (1.f + Ei) * (1.f + Eg);
      const float F = 1.f + Ef;
      const float t2 = (1.f - Eg) * F;
      const float t2s =
          copysignf(t2, __uint_as_float(__float_as_uint(zg) ^ 0x80000000u));
      const float cn = fmaf(cc[i], Pig, t2s) * __builtin_amdgcn_rcpf(F * Pig);
      cc[i] = cn;
      const float Ec = __builtin_amdgcn_exp2f(fabsf(cn) * N2L2E);
      float hn = (1.f - Ec) * __builtin_amdgcn_rcpf((1.f + Eo) * (1.f + Ec));
      hn = copysignf(hn, cn);
      const unsigned c1 = cvtpk(hn, hn);          // hi component (both halves)
      const float r1 = hn - pklo(c1);
      const unsigned c2 = cvtpk(r1, r1);          // lo component
      if (jv && owner) {
        ringU[wrBase + (unsigned)(J * SEQPW * 40 + i * 40)]      = (unsigned short)c1;
        ringU[wrBase + (unsigned)(J * SEQPW * 40 + i * 40 + 16)] = (unsigned short)c2;
        if constexpr (OUTM == 1)
          fstw[(4 * (q & 1) + i) * 112 + J * 14 + col] = hn;
      }
    }
  };

  // flush ring hi halves -> global bf16 hi plane (full 64B lines)
  auto flushY8 = [&](int sBase) {
    const int sq = lane >> 2, part = lane & 3;
#pragma unroll
    for (int rr = 0; rr < 2; ++rr) {
      const int r = 2 * part + rr;  // slot = step offset within the block
      const int tg = dir ? (63 - (sBase + r)) : (sBase + r);
      const unsigned* src =
          ringD + ((unsigned)(w * 8 + r) * SEQPW + (unsigned)sq) * 20u;
      const uint4 h0 = *(const uint4*)(src);
      const uint4 h1 = *(const uint4*)(src + 4);
      char* gph = (char*)yhiP + ((sb + (unsigned)sq) * 64u + (unsigned)tg) * 32u;
      *(uint4*)(gph) = h0; *(uint4*)(gph + 16) = h1;
    }
  };
  auto flushO = [&](int tbase) {  // fp32 out: 448B/seq contiguous, coalesced
    const int sq = lane >> 3, part = lane & 7;
    char* gp = (char*)yf + ((sb + (unsigned)sq) * 64u + (unsigned)tbase) * 56u;
    const float* src = fstw + sq * 112 + part;
#pragma unroll
    for (int m = 0; m < 14; ++m)
      *(float*)(gp + (part + 8 * m) * 4) = src[8 * m];
  };

  // x offset for step index k (clamped at the tail; clamped loads feed only
  // dead XCALC results)
  auto XO = [&](int k) { return voff0 + (k > 63 ? 63 : k) * dsx; };

  float fb0[8], fb1[8], fb2[8], fb3[8], fb4[8], fb5[8], fb6[8], fb7[8];
  unsigned ub0[4], ub1[4], ub2[4], ub3[4], ub4[4], ub5[4], ub6[4], ub7[4];
  f32x4 axP[4], axQ[4];

  LOADX(fb0, ub0, XO(0));
  LOADX(fb1, ub1, XO(1));
  LOADX(fb2, ub2, XO(2));
  LOADX(fb3, ub3, XO(3));
  LOADX(fb4, ub4, XO(4));
  XCALC(fb0, ub0, axP);  // ax for step 0

#pragma unroll 1
  for (int s = 0; s < T; s += 8) {
    LOADX(fb5, ub5, XO(s + 5));
    LOADX(fb6, ub6, XO(s + 6));
    STEP(icx<0>{}, fb1, ub1, axP, axQ);
    STEP(icx<1>{}, fb2, ub2, axQ, axP);
    LOADX(fb7, ub7, XO(s + 7));
    LOADX(fb0, ub0, XO(s + 8));
    STEP(icx<2>{}, fb3, ub3, axP, axQ);
    STEP(icx<3>{}, fb4, ub4, axQ, axP);
    LOADX(fb1, ub1, XO(s + 9));
    LOADX(fb2, ub2, XO(s + 10));
    STEP(icx<4>{}, fb5, ub5, axP, axQ);
    STEP(icx<5>{}, fb6, ub6, axQ, axP);
    LOADX(fb3, ub3, XO(s + 11));
    LOADX(fb4, ub4, XO(s + 12));
    STEP(icx<6>{}, fb7, ub7, axP, axQ);
    STEP(icx<7>{}, fb0, ub0, axQ, axP);
    if constexpr (OUTM == 0) flushY8(s); else flushO(s);
  }
}

extern "C" void kernel_launch(void* const* d_in, const int* in_sizes, int n_in,
                              void* d_out, int out_size, void* d_ws, size_t ws_size,
                              hipStream_t stream) {
  const float* x     = (const float*)d_in[0];
  const float* wih1f = (const float*)d_in[1];
  const float* whh1f = (const float*)d_in[2];
  const float* bih1f = (const float*)d_in[3];
  const float* bhh1f = (const float*)d_in[4];
  const float* wih1b = (const float*)d_in[5];
  const float* whh1b = (const float*)d_in[6];
  const float* bih1b = (const float*)d_in[7];
  const float* bhh1b = (const float*)d_in[8];
  const float* wih2f = (const float*)d_in[9];
  const float* whh2f = (const float*)d_in[10];
  const float* bih2f = (const float*)d_in[11];
  const float* bhh2f = (const float*)d_in[12];
  const float* wih2b = (const float*)d_in[13];
  const float* whh2b = (const float*)d_in[14];
  const float* bih2b = (const float*)d_in[15];
  const float* bhh2b = (const float*)d_in[16];
  const float* wih3  = (const float*)d_in[17];
  const float* whh3  = (const float*)d_in[18];
  const float* bih3  = (const float*)d_in[19];
  const float* bhh3  = (const float*)d_in[20];

  using usp = unsigned short*;
  const size_t PL = (size_t)BATCH * T * 16;  // ushorts per plane (padded 16ch)
  usp y1fh = (usp)d_ws;
  usp y1bh = y1fh + PL;
  usp y2fh = y1bh + PL;
  usp y2bh = y2fh + PL;
  float* out = (float*)d_out;

  const dim3 blk(256);
  const dim3 grid_bi(BATCH / 64, 2);
  const dim3 grid_uni(BATCH / 32, 1);  // SEQPW=8 -> 2 waves/SIMD

  lstm_k<0, 0, 16><<<grid_bi, blk, 0, stream>>>(
      x, nullptr, nullptr,
      wih1f, whh1f, bih1f, bhh1f, wih1b, whh1b, bih1b, bhh1b,
      y1fh, y1bh, nullptr);
  lstm_k<1, 0, 16><<<grid_bi, blk, 0, stream>>>(
      nullptr, y1fh, y1bh,
      wih2f, whh2f, bih2f, bhh2f, wih2b, whh2b, bih2b, bhh2b,
      y2fh, y2bh, nullptr);
  lstm_k<1, 1, 8><<<grid_uni, blk, 0, stream>>>(
      nullptr, y2fh, y2bh,
      wih3, whh3, bih3, bhh3, wih3, whh3, bih3, bhh3,
      nullptr, nullptr, out);
}

// Round 13
// 202.542 us; speedup vs baseline: 2.3173x; 1.2230x over previous
//
#include <hip/hip_runtime.h>

#define DEV __device__ __forceinline__

typedef short bf16x8 __attribute__((ext_vector_type(8)));
typedef float f32x4 __attribute__((ext_vector_type(4)));

constexpr int BATCH = 16384, T = 64, H = 14;
constexpr float NL2E  = -1.4426950408889634f;   // -log2(e)
constexpr float N2L2E = -2.8853900817779268f;   // -2*log2(e)

union FragU { bf16x8 v; unsigned u[4]; };

template <int N> struct icx { static constexpr int value = N; };

struct __attribute__((packed, aligned(4))) u4u { uint4 v; };  // 4B-aligned 16B load

DEV unsigned cvtpk(float lo, float hi) {
  unsigned r;
  asm("v_cvt_pk_bf16_f32 %0, %1, %2" : "=v"(r) : "v"(lo), "v"(hi));
  return r;
}
DEV float pklo(unsigned u) { return __uint_as_float(u << 16); }
DEV float pkhi(unsigned u) { return __uint_as_float(u & 0xffff0000u); }

DEV f32x4 MFMA(FragU a, FragU b, f32x4 c) {
  return __builtin_amdgcn_mfma_f32_16x16x32_bf16(a.v, b.v, c, 0, 0, 0);
}

// One LSTM layer; one direction per blockIdx.y; one wave = SEQPW sequences.
// h lives in an 8-slot LDS ring of bf16 hi/lo component planes; the hi half
// of the ring IS the y staging buffer (flushed to the global hi plane every
// 8 steps as full 64B lines). Inter-layer x is single-bf16 (hi plane only).
// x-path weights are single-component (W1 only: the dropped x*W2 term is the
// same 2^-9-relative magnitude as the x-bf16 quantization, measured free);
// recurrent U keeps 2 components, L1 keeps exact fp32 x against W1 via the
// value|residual section split. Bias enters as the MFMA C-operand.
// Weights/bias pre-scaled by -log2e (-2log2e for g). x prefetched 4-5 steps
// ahead (8-buffer rotation); 8-step unrolled loop -> LDS addresses immediate.
// INM: 0 = fp32 x [seq][t][13] (layer1) ; 1 = bf16 hi-plane x (layers 2,3)
// OUTM: 0 = bf16 hi-plane y ; 1 = fp32 y [seq][t][14] (layer 3, SEQPW=8)
template <int INM, int OUTM, int SEQPW>
__global__ __launch_bounds__(256, 2) void lstm_k(
    const float* __restrict__ xf,
    const unsigned short* __restrict__ xfh,
    const unsigned short* __restrict__ xbh,
    const float* __restrict__ wihF, const float* __restrict__ whhF,
    const float* __restrict__ bihF, const float* __restrict__ bhhF,
    const float* __restrict__ wihB, const float* __restrict__ whhB,
    const float* __restrict__ bihB, const float* __restrict__ bhhB,
    unsigned short* __restrict__ yFh, unsigned short* __restrict__ yBh,
    float* __restrict__ yf)
{
  constexpr int IN = (INM == 0) ? 13 : 28;
  const int dir = (OUTM == 1) ? 0 : blockIdx.y;
  const float* __restrict__ wih = dir ? wihB : wihF;
  const float* __restrict__ whh = dir ? whhB : whhF;
  const float* __restrict__ bih = dir ? bihB : bihF;
  const float* __restrict__ bhh = dir ? bhhB : bhhF;
  unsigned short* __restrict__ yhiP = dir ? yBh : yFh;

  const int tid = threadIdx.x;
  const int w = tid >> 6, lane = tid & 63;
  const int col = lane & 15, q = lane >> 4;
  const int qodd = q & 1, qhi = q >> 1;
  const int scol = col & (SEQPW - 1);
  const bool jv = col < H;
  const int jc = jv ? col : 13;
  const int qe = (SEQPW == 16) ? q : (q & 1);
  const bool owner = (SEQPW == 16) || (q < 2);

  // ring: [wave][slot 0..7][seq][ hc1 dw0..7 | hc2 dw8..15 | pad dw16..19 ]
  __shared__ unsigned ringS[4][8][SEQPW][20];
  __shared__ __align__(16) float fst_s[OUTM == 1 ? 4 * 8 * 8 * 14 : 4];
  unsigned* const ringD = &ringS[0][0][0][0];
  unsigned short* const ringU = (unsigned short*)ringD;
  float* const fstw = fst_s + ((OUTM == 1) ? w * 896 : 0);

  {  // zero the WHOLE per-wave ring (slot 7 = step-0 h; ch 14/15 stay 0
     // forever: they feed MFMAs against zero B-cols and flush to y planes)
    unsigned* rz = ringD + (unsigned)(w * 8 * SEQPW) * 20u;
    for (int i = lane; i < 8 * SEQPW * 20; i += 64) rz[i] = 0u;
  }

  // ---------------- B fragments + fp32 bias C0 (built once) ----------------
  FragU Bx1[4], Bh1[4], Bh2[4];
  f32x4 bbq[4];
#pragma unroll
  for (int g = 0; g < 4; ++g) {
    const int grow = g * H + jc;
    const float sc = (g == 2) ? N2L2E : NL2E;
    const float bsc = jv ? (bih[grow] + bhh[grow]) * sc : 0.f;
    bbq[g] = (f32x4){bsc, bsc, bsc, bsc};
    const float* __restrict__ wr = wih + grow * IN;
    const float* __restrict__ ur = whh + grow * H;
#pragma unroll
    for (int p = 0; p < 4; ++p) {
      {  // x weights: single component W1
        float wa = 0.f, wb = 0.f;
        const int l0 = 8 * qodd + 2 * p;
        if (INM == 0) {  // 13 ch; sec0 = x values, sec1 = x residuals (same W1)
          if (jv && l0 < 13) wa = wr[l0] * sc;
          if (jv && l0 + 1 < 13) wb = wr[l0 + 1] * sc;
        } else {         // plane-local ch; wih col = qhi*14 + l
          if (jv && l0 < 14) wa = wr[qhi * 14 + l0] * sc;
          if (jv && l0 + 1 < 14) wb = wr[qhi * 14 + l0 + 1] * sc;
        }
        Bx1[g].u[p] = cvtpk(wa, wb);
      }
      {  // h weights (2 components): Bh1=[U1|U1], Bh2=[U2|U2]
        const int m0 = 8 * qodd + 2 * p;
        const float ua = (jv && m0 < 14) ? ur[m0] * sc : 0.f;
        const float ub = (jv && (m0 + 1) < 14) ? ur[m0 + 1] * sc : 0.f;
        const unsigned c1 = cvtpk(ua, ub);
        const float ra = ua - pklo(c1), rb = ub - pkhi(c1);
        const unsigned c2 = cvtpk(ra, rb);
        Bh1[g].u[p] = c1;
        Bh2[g].u[p] = c2;
      }
    }
  }

  const unsigned sb = (unsigned)blockIdx.x * (4u * SEQPW) + (unsigned)w * SEQPW;
  const unsigned arow = sb + (unsigned)scol;

  // LDS bases (all per-step addresses = base + compile-time immediate)
  const unsigned rdBase = ((unsigned)(w * 8) * SEQPW + (unsigned)scol) * 20u +
                          (unsigned)(qhi * 8 + qodd * 4);
  const unsigned wrBase =
      ((unsigned)(w * 8) * SEQPW + (unsigned)(4 * qe)) * 40u + (unsigned)col;

  const int t0 = dir ? T - 1 : 0;
  const int dsx = (INM == 0) ? (dir ? -52 : 52) : (dir ? -32 : 32);
  int voff0;
  if constexpr (INM == 0)
    voff0 = (int)((arow * 64u + (unsigned)t0) * 52u) + qodd * 32;
  else
    voff0 = (int)((arow * 64u + (unsigned)t0) * 32u) + qodd * 16;
  const unsigned short* __restrict__ xph = (INM == 0) ? nullptr : (qhi ? xbh : xfh);

  float cc[4] = {0.f, 0.f, 0.f, 0.f};

  auto loadf = [&](float (&dst)[8], int off) {
    const char* pa = (const char*)xf + off;
    if (!qodd) {  // floats 0..7: two 4B-aligned 16B loads
      const uint4 a = ((const u4u*)pa)->v;
      const uint4 b = ((const u4u*)(pa + 16))->v;
      dst[0] = __uint_as_float(a.x); dst[1] = __uint_as_float(a.y);
      dst[2] = __uint_as_float(a.z); dst[3] = __uint_as_float(a.w);
      dst[4] = __uint_as_float(b.x); dst[5] = __uint_as_float(b.y);
      dst[6] = __uint_as_float(b.z); dst[7] = __uint_as_float(b.w);
    } else {      // floats 8..12 valid; clamp tail (B-side zeros kill clones)
      const uint4 a = ((const u4u*)pa)->v;
      dst[0] = __uint_as_float(a.x); dst[1] = __uint_as_float(a.y);
      dst[2] = __uint_as_float(a.z); dst[3] = __uint_as_float(a.w);
      dst[4] = *(const float*)(pa + 16);
      dst[5] = dst[6] = dst[7] = dst[4];
    }
  };
  auto loadu = [&](unsigned (&dst)[4], int off) {
    const uint4 a = *(const uint4*)((const char*)xph + off);
    dst[0] = a.x; dst[1] = a.y; dst[2] = a.z; dst[3] = a.w;
  };
  auto LOADX = [&](float (&df)[8], unsigned (&du)[4], int off) {
    if constexpr (INM == 0) loadf(df, off); else loadu(du, off);
  };

  // x-side MFMA block (independent of h): ax = bias + x*W1
  auto XCALC = [&](float (&xfb)[8], unsigned (&xub)[4], f32x4 (&ax)[4]) {
    FragU Ax1;
    if constexpr (INM == 0) {
      unsigned c[4];
#pragma unroll
      for (int p = 0; p < 4; ++p) c[p] = cvtpk(xfb[2 * p], xfb[2 * p + 1]);
      if (qhi) {  // sec1 lanes carry the residual component
#pragma unroll
        for (int p = 0; p < 4; ++p) {
          const float ra = xfb[2 * p] - pklo(c[p]);
          const float rb = xfb[2 * p + 1] - pkhi(c[p]);
          c[p] = cvtpk(ra, rb);
        }
      }
#pragma unroll
      for (int p = 0; p < 4; ++p) Ax1.u[p] = c[p];
    } else {
#pragma unroll
      for (int p = 0; p < 4; ++p) Ax1.u[p] = xub[p];
    }
#pragma unroll
    for (int g = 0; g < 4; ++g)
      ax[g] = MFMA(Ax1, Bx1[g], bbq[g]);  // bias + x*W1 (L1: exact-x * W1)
  };

  // One recurrent step. J = compile-time slot index (step s+J, s%8==0).
  auto STEP = [&](auto Jc, float (&nf)[8], unsigned (&nu)[4],
                  f32x4 (&cur)[4], f32x4 (&nxt)[4]) {
    constexpr int J = decltype(Jc)::value;
    constexpr int SLOT_R = (J + 7) & 7;
    // 1. h fragment from ring (single b128; static slot offset)
    FragU A12;
    {
      const uint4 t4 =
          *(const uint4*)(ringD + rdBase + (unsigned)(SLOT_R * SEQPW * 20));
      A12.u[0] = t4.x; A12.u[1] = t4.y; A12.u[2] = t4.z; A12.u[3] = t4.w;
    }
    // 2. next step's x block (fills the ds_read shadow)
    XCALC(nf, nu, nxt);
    // 3. h-chain (depth 2) accumulated onto the pipelined x result
    f32x4 z[4];
#pragma unroll
    for (int g = 0; g < 4; ++g)
      z[g] = MFMA(A12, Bh2[g], MFMA(A12, Bh1[g], cur[g]));
    // 4. activations (pre-scaled: z' = -log2e*z ; g: -2log2e*z)
#pragma unroll
    for (int i = 0; i < 4; ++i) {
      const float zi = z[0][i], zf = z[1][i], zg = z[2][i], zo = z[3][i];
      const float Ei = __builtin_amdgcn_exp2f(zi);
      const float Ef = __builtin_amdgcn_exp2f(zf);
      const float Eo = __builtin_amdgcn_exp2f(zo);
      const float Eg = __builtin_amdgcn_exp2f(-fabsf(zg));
      const float Pig = (1.f + Ei) * (1.f + Eg);
      const float F = 1.f + Ef;
      const float t2 = (1.f - Eg) * F;
      const float t2s =
          copysignf(t2, __uint_as_float(__float_as_uint(zg) ^ 0x80000000u));
      const float cn = fmaf(cc[i], Pig, t2s) * __builtin_amdgcn_rcpf(F * Pig);
      cc[i] = cn;
      const float Ec = __builtin_amdgcn_exp2f(fabsf(cn) * N2L2E);
      float hn = (1.f - Ec) * __builtin_amdgcn_rcpf((1.f + Eo) * (1.f + Ec));
      hn = copysignf(hn, cn);
      const unsigned c1 = cvtpk(hn, hn);          // hi component (both halves)
      const float r1 = hn - pklo(c1);
      const unsigned c2 = cvtpk(r1, r1);          // lo component
      if (jv && owner) {
        ringU[wrBase + (unsigned)(J * SEQPW * 40 + i * 40)]      = (unsigned short)c1;
        ringU[wrBase + (unsigned)(J * SEQPW * 40 + i * 40 + 16)] = (unsigned short)c2;
        if constexpr (OUTM == 1)
          fstw[(4 * (q & 1) + i) * 112 + J * 14 + col] = hn;
      }
    }
  };

  // flush ring hi halves -> global bf16 hi plane (full 64B lines)
  auto flushY8 = [&](int sBase) {
    const int sq = lane >> 2, part = lane & 3;
#pragma unroll
    for (int rr = 0; rr < 2; ++rr) {
      const int r = 2 * part + rr;  // slot = step offset within the block
      const int tg = dir ? (63 - (sBase + r)) : (sBase + r);
      const unsigned* src =
          ringD + ((unsigned)(w * 8 + r) * SEQPW + (unsigned)sq) * 20u;
      const uint4 h0 = *(const uint4*)(src);
      const uint4 h1 = *(const uint4*)(src + 4);
      char* gph = (char*)yhiP + ((sb + (unsigned)sq) * 64u + (unsigned)tg) * 32u;
      *(uint4*)(gph) = h0; *(uint4*)(gph + 16) = h1;
    }
  };
  auto flushO = [&](int tbase) {  // fp32 out: 448B/seq contiguous, coalesced
    const int sq = lane >> 3, part = lane & 7;
    char* gp = (char*)yf + ((sb + (unsigned)sq) * 64u + (unsigned)tbase) * 56u;
    const float* src = fstw + sq * 112 + part;
#pragma unroll
    for (int m = 0; m < 14; ++m)
      *(float*)(gp + (part + 8 * m) * 4) = src[8 * m];
  };

  // x offset for step index k (clamped at the tail; clamped loads feed only
  // dead XCALC results)
  auto XO = [&](int k) { return voff0 + (k > 63 ? 63 : k) * dsx; };

  float fb0[8], fb1[8], fb2[8], fb3[8], fb4[8], fb5[8], fb6[8], fb7[8];
  unsigned ub0[4], ub1[4], ub2[4], ub3[4], ub4[4], ub5[4], ub6[4], ub7[4];
  f32x4 axP[4], axQ[4];

  LOADX(fb0, ub0, XO(0));
  LOADX(fb1, ub1, XO(1));
  LOADX(fb2, ub2, XO(2));
  LOADX(fb3, ub3, XO(3));
  LOADX(fb4, ub4, XO(4));
  XCALC(fb0, ub0, axP);  // ax for step 0

#pragma unroll 1
  for (int s = 0; s < T; s += 8) {
    LOADX(fb5, ub5, XO(s + 5));
    LOADX(fb6, ub6, XO(s + 6));
    STEP(icx<0>{}, fb1, ub1, axP, axQ);
    STEP(icx<1>{}, fb2, ub2, axQ, axP);
    LOADX(fb7, ub7, XO(s + 7));
    LOADX(fb0, ub0, XO(s + 8));
    STEP(icx<2>{}, fb3, ub3, axP, axQ);
    STEP(icx<3>{}, fb4, ub4, axQ, axP);
    LOADX(fb1, ub1, XO(s + 9));
    LOADX(fb2, ub2, XO(s + 10));
    STEP(icx<4>{}, fb5, ub5, axP, axQ);
    STEP(icx<5>{}, fb6, ub6, axQ, axP);
    LOADX(fb3, ub3, XO(s + 11));
    LOADX(fb4, ub4, XO(s + 12));
    STEP(icx<6>{}, fb7, ub7, axP, axQ);
    STEP(icx<7>{}, fb0, ub0, axQ, axP);
    if constexpr (OUTM == 0) flushY8(s); else flushO(s);
  }
}

extern "C" void kernel_launch(void* const* d_in, const int* in_sizes, int n_in,
                              void* d_out, int out_size, void* d_ws, size_t ws_size,
                              hipStream_t stream) {
  const float* x     = (const float*)d_in[0];
  const float* wih1f = (const float*)d_in[1];
  const float* whh1f = (const float*)d_in[2];
  const float* bih1f = (const float*)d_in[3];
  const float* bhh1f = (const float*)d_in[4];
  const float* wih1b = (const float*)d_in[5];
  const float* whh1b = (const float*)d_in[6];
  const float* bih1b = (const float*)d_in[7];
  const float* bhh1b = (const float*)d_in[8];
  const float* wih2f = (const float*)d_in[9];
  const float* whh2f = (const float*)d_in[10];
  const float* bih2f = (const float*)d_in[11];
  const float* bhh2f = (const float*)d_in[12];
  const float* wih2b = (const float*)d_in[13];
  const float* whh2b = (const float*)d_in[14];
  const float* bih2b = (const float*)d_in[15];
  const float* bhh2b = (const float*)d_in[16];
  const float* wih3  = (const float*)d_in[17];
  const float* whh3  = (const float*)d_in[18];
  const float* bih3  = (const float*)d_in[19];
  const float* bhh3  = (const float*)d_in[20];

  using usp = unsigned short*;
  const size_t PL = (size_t)BATCH * T * 16;  // ushorts per plane (padded 16ch)
  usp y1fh = (usp)d_ws;
  usp y1bh = y1fh + PL;
  usp y2fh = y1bh + PL;
  usp y2bh = y2fh + PL;
  float* out = (float*)d_out;

  const dim3 blk(256);
  const dim3 grid_bi(BATCH / 64, 2);
  const dim3 grid_uni(BATCH / 32, 1);  // SEQPW=8 -> 2 waves/SIMD

  lstm_k<0, 0, 16><<<grid_bi, blk, 0, stream>>>(
      x, nullptr, nullptr,
      wih1f, whh1f, bih1f, bhh1f, wih1b, whh1b, bih1b, bhh1b,
      y1fh, y1bh, nullptr);
  lstm_k<1, 0, 16><<<grid_bi, blk, 0, stream>>>(
      nullptr, y1fh, y1bh,
      wih2f, whh2f, bih2f, bhh2f, wih2b, whh2b, bih2b, bhh2b,
      y2fh, y2bh, nullptr);
  lstm_k<1, 1, 8><<<grid_uni, blk, 0, stream>>>(
      nullptr, y2fh, y2bh,
      wih3, whh3, bih3, bhh3, wih3, whh3, bih3, bhh3,
      nullptr, nullptr, out);
}

// Round 14
// 183.106 us; speedup vs baseline: 2.5632x; 1.1061x over previous
//
#include <hip/hip_runtime.h>

#define DEV __device__ __forceinline__

typedef short bf16x8 __attribute__((ext_vector_type(8)));
typedef float f32x4 __attribute__((ext_vector_type(4)));

constexpr int BATCH = 16384, T = 64, H = 14;
constexpr float NL2E  = -1.4426950408889634f;   // -log2(e)
constexpr float N2L2E = -2.8853900817779268f;   // -2*log2(e)

union FragU { bf16x8 v; unsigned u[4]; };

template <int N> struct icx { static constexpr int value = N; };

struct __attribute__((packed, aligned(4))) u4u { uint4 v; };  // 4B-aligned 16B load

DEV unsigned cvtpk(float lo, float hi) {
  unsigned r;
  asm("v_cvt_pk_bf16_f32 %0, %1, %2" : "=v"(r) : "v"(lo), "v"(hi));
  return r;
}
DEV float pklo(unsigned u) { return __uint_as_float(u << 16); }
DEV float pkhi(unsigned u) { return __uint_as_float(u & 0xffff0000u); }

DEV f32x4 MFMA(FragU a, FragU b, f32x4 c) {
  return __builtin_amdgcn_mfma_f32_16x16x32_bf16(a.v, b.v, c, 0, 0, 0);
}

// One LSTM layer; one direction per blockIdx.y; one wave = SEQPW sequences.
// h lives in an 8-slot LDS ring of bf16 planes (hi component only); the ring
// IS the y staging buffer (flushed to the global hi plane every 8 steps as
// full 64B lines). Recurrent h-path is a SINGLE MFMA per gate: A = [h1|h1]
// (both k-sections read the same bf16 h), B = [U1|U2] (weight keeps 2
// components) -> z += h1*(U1+U2); only the h state is bf16-quantized.
// x-path weights single-component; L1 keeps exact fp32 x via the
// value|residual section split. Bias enters as the MFMA C-operand.
// Weights/bias pre-scaled by -log2e (-2log2e for g). x prefetched 4-5 steps
// ahead (8-buffer rotation); 8-step unrolled loop -> LDS addresses immediate.
// INM: 0 = fp32 x [seq][t][13] (layer1) ; 1 = bf16 hi-plane x (layers 2,3)
// OUTM: 0 = bf16 hi-plane y ; 1 = fp32 y [seq][t][14] (layer 3, SEQPW=8)
template <int INM, int OUTM, int SEQPW>
__global__ __launch_bounds__(256, 2) void lstm_k(
    const float* __restrict__ xf,
    const unsigned short* __restrict__ xfh,
    const unsigned short* __restrict__ xbh,
    const float* __restrict__ wihF, const float* __restrict__ whhF,
    const float* __restrict__ bihF, const float* __restrict__ bhhF,
    const float* __restrict__ wihB, const float* __restrict__ whhB,
    const float* __restrict__ bihB, const float* __restrict__ bhhB,
    unsigned short* __restrict__ yFh, unsigned short* __restrict__ yBh,
    float* __restrict__ yf)
{
  constexpr int IN = (INM == 0) ? 13 : 28;
  const int dir = (OUTM == 1) ? 0 : blockIdx.y;
  const float* __restrict__ wih = dir ? wihB : wihF;
  const float* __restrict__ whh = dir ? whhB : whhF;
  const float* __restrict__ bih = dir ? bihB : bihF;
  const float* __restrict__ bhh = dir ? bhhB : bhhF;
  unsigned short* __restrict__ yhiP = dir ? yBh : yFh;

  const int tid = threadIdx.x;
  const int w = tid >> 6, lane = tid & 63;
  const int col = lane & 15, q = lane >> 4;
  const int qodd = q & 1, qhi = q >> 1;
  const int scol = col & (SEQPW - 1);
  const bool jv = col < H;
  const int jc = jv ? col : 13;
  const int qe = (SEQPW == 16) ? q : (q & 1);
  const bool owner = (SEQPW == 16) || (q < 2);

  // ring: [wave][slot 0..7][seq][ hc1 dw0..7 | pad dw8..11 ]
  __shared__ unsigned ringS[4][8][SEQPW][12];
  __shared__ __align__(16) float fst_s[OUTM == 1 ? 4 * 8 * 8 * 14 : 4];
  unsigned* const ringD = &ringS[0][0][0][0];
  unsigned short* const ringU = (unsigned short*)ringD;
  float* const fstw = fst_s + ((OUTM == 1) ? w * 896 : 0);

  {  // zero the WHOLE per-wave ring (slot 7 = step-0 h; ch 14/15 stay 0
     // forever: they feed MFMAs against zero B-cols and flush to y planes)
    unsigned* rz = ringD + (unsigned)(w * 8 * SEQPW) * 12u;
    for (int i = lane; i < 8 * SEQPW * 12; i += 64) rz[i] = 0u;
  }

  // ---------------- B fragments + fp32 bias C0 (built once) ----------------
  FragU Bx1[4], Bh1[4];
  f32x4 bbq[4];
#pragma unroll
  for (int g = 0; g < 4; ++g) {
    const int grow = g * H + jc;
    const float sc = (g == 2) ? N2L2E : NL2E;
    const float bsc = jv ? (bih[grow] + bhh[grow]) * sc : 0.f;
    bbq[g] = (f32x4){bsc, bsc, bsc, bsc};
    const float* __restrict__ wr = wih + grow * IN;
    const float* __restrict__ ur = whh + grow * H;
#pragma unroll
    for (int p = 0; p < 4; ++p) {
      {  // x weights: single component W1
        float wa = 0.f, wb = 0.f;
        const int l0 = 8 * qodd + 2 * p;
        if (INM == 0) {  // 13 ch; sec0 = x values, sec1 = x residuals (same W1)
          if (jv && l0 < 13) wa = wr[l0] * sc;
          if (jv && l0 + 1 < 13) wb = wr[l0 + 1] * sc;
        } else {         // plane-local ch; wih col = qhi*14 + l
          if (jv && l0 < 14) wa = wr[qhi * 14 + l0] * sc;
          if (jv && l0 + 1 < 14) wb = wr[qhi * 14 + l0 + 1] * sc;
        }
        Bx1[g].u[p] = cvtpk(wa, wb);
      }
      {  // h weights: sec0 (q<2) carries U1, sec1 (q>=2) carries U2 residual
        const int m0 = 8 * qodd + 2 * p;
        const float ua = (jv && m0 < 14) ? ur[m0] * sc : 0.f;
        const float ub = (jv && (m0 + 1) < 14) ? ur[m0 + 1] * sc : 0.f;
        const unsigned c1 = cvtpk(ua, ub);
        const float ra = ua - pklo(c1), rb = ub - pkhi(c1);
        const unsigned c2 = cvtpk(ra, rb);
        Bh1[g].u[p] = qhi ? c2 : c1;
      }
    }
  }

  const unsigned sb = (unsigned)blockIdx.x * (4u * SEQPW) + (unsigned)w * SEQPW;
  const unsigned arow = sb + (unsigned)scol;

  // LDS bases (all per-step addresses = base + compile-time immediate).
  // All four q-groups of a seq read the SAME hc1 dwords (broadcast).
  const unsigned rdBase =
      ((unsigned)(w * 8) * SEQPW + (unsigned)scol) * 12u + (unsigned)(qodd * 4);
  const unsigned wrBase =
      ((unsigned)(w * 8) * SEQPW + (unsigned)(4 * qe)) * 24u + (unsigned)col;

  const int t0 = dir ? T - 1 : 0;
  const int dsx = (INM == 0) ? (dir ? -52 : 52) : (dir ? -32 : 32);
  int voff0;
  if constexpr (INM == 0)
    voff0 = (int)((arow * 64u + (unsigned)t0) * 52u) + qodd * 32;
  else
    voff0 = (int)((arow * 64u + (unsigned)t0) * 32u) + qodd * 16;
  const unsigned short* __restrict__ xph = (INM == 0) ? nullptr : (qhi ? xbh : xfh);

  float cc[4] = {0.f, 0.f, 0.f, 0.f};

  auto loadf = [&](float (&dst)[8], int off) {
    const char* pa = (const char*)xf + off;
    if (!qodd) {  // floats 0..7: two 4B-aligned 16B loads
      const uint4 a = ((const u4u*)pa)->v;
      const uint4 b = ((const u4u*)(pa + 16))->v;
      dst[0] = __uint_as_float(a.x); dst[1] = __uint_as_float(a.y);
      dst[2] = __uint_as_float(a.z); dst[3] = __uint_as_float(a.w);
      dst[4] = __uint_as_float(b.x); dst[5] = __uint_as_float(b.y);
      dst[6] = __uint_as_float(b.z); dst[7] = __uint_as_float(b.w);
    } else {      // floats 8..12 valid; clamp tail (B-side zeros kill clones)
      const uint4 a = ((const u4u*)pa)->v;
      dst[0] = __uint_as_float(a.x); dst[1] = __uint_as_float(a.y);
      dst[2] = __uint_as_float(a.z); dst[3] = __uint_as_float(a.w);
      dst[4] = *(const float*)(pa + 16);
      dst[5] = dst[6] = dst[7] = dst[4];
    }
  };
  auto loadu = [&](unsigned (&dst)[4], int off) {
    const uint4 a = *(const uint4*)((const char*)xph + off);
    dst[0] = a.x; dst[1] = a.y; dst[2] = a.z; dst[3] = a.w;
  };
  auto LOADX = [&](float (&df)[8], unsigned (&du)[4], int off) {
    if constexpr (INM == 0) loadf(df, off); else loadu(du, off);
  };

  // x-side MFMA block (independent of h): ax = bias + x*W1
  auto XCALC = [&](float (&xfb)[8], unsigned (&xub)[4], f32x4 (&ax)[4]) {
    FragU Ax1;
    if constexpr (INM == 0) {
      unsigned c[4];
#pragma unroll
      for (int p = 0; p < 4; ++p) c[p] = cvtpk(xfb[2 * p], xfb[2 * p + 1]);
      if (qhi) {  // sec1 lanes carry the residual component
#pragma unroll
        for (int p = 0; p < 4; ++p) {
          const float ra = xfb[2 * p] - pklo(c[p]);
          const float rb = xfb[2 * p + 1] - pkhi(c[p]);
          c[p] = cvtpk(ra, rb);
        }
      }
#pragma unroll
      for (int p = 0; p < 4; ++p) Ax1.u[p] = c[p];
    } else {
#pragma unroll
      for (int p = 0; p < 4; ++p) Ax1.u[p] = xub[p];
    }
#pragma unroll
    for (int g = 0; g < 4; ++g)
      ax[g] = MFMA(Ax1, Bx1[g], bbq[g]);  // bias + x*W1 (L1: exact-x * W1)
  };

  // One recurrent step. J = compile-time slot index (step s+J, s%8==0).
  auto STEP = [&](auto Jc, float (&nf)[8], unsigned (&nu)[4],
                  f32x4 (&cur)[4], f32x4 (&nxt)[4]) {
    constexpr int J = decltype(Jc)::value;
    constexpr int SLOT_R = (J + 7) & 7;
    // 1. h fragment from ring (single b128, broadcast across q-groups)
    FragU A12;
    {
      const uint4 t4 =
          *(const uint4*)(ringD + rdBase + (unsigned)(SLOT_R * SEQPW * 12));
      A12.u[0] = t4.x; A12.u[1] = t4.y; A12.u[2] = t4.z; A12.u[3] = t4.w;
    }
    // 2. next step's x block (fills the ds_read shadow)
    XCALC(nf, nu, nxt);
    // 3. h-chain: ONE MFMA per gate -> z = ax + h1*(U1+U2)
    f32x4 z[4];
#pragma unroll
    for (int g = 0; g < 4; ++g)
      z[g] = MFMA(A12, Bh1[g], cur[g]);
    // 4. activations (pre-scaled: z' = -log2e*z ; g: -2log2e*z)
#pragma unroll
    for (int i = 0; i < 4; ++i) {
      const float zi = z[0][i], zf = z[1][i], zg = z[2][i], zo = z[3][i];
      const float Ei = __builtin_amdgcn_exp2f(zi);
      const float Ef = __builtin_amdgcn_exp2f(zf);
      const float Eo = __builtin_amdgcn_exp2f(zo);
      const float Eg = __builtin_amdgcn_exp2f(-fabsf(zg));
      const float Pig = (1.f + Ei) * (1.f + Eg);
      const float F = 1.f + Ef;
      const float t2 = (1.f - Eg) * F;
      const float t2s =
          copysignf(t2, __uint_as_float(__float_as_uint(zg) ^ 0x80000000u));
      const float cn = fmaf(cc[i], Pig, t2s) * __builtin_amdgcn_rcpf(F * Pig);
      cc[i] = cn;
      const float Ec = __builtin_amdgcn_exp2f(fabsf(cn) * N2L2E);
      float hn = (1.f - Ec) * __builtin_amdgcn_rcpf((1.f + Eo) * (1.f + Ec));
      hn = copysignf(hn, cn);
      const unsigned c1 = cvtpk(hn, hn);          // bf16 h (both halves)
      if (jv && owner) {
        ringU[wrBase + (unsigned)(J * SEQPW * 24 + i * 24)] = (unsigned short)c1;
        if constexpr (OUTM == 1)
          fstw[(4 * (q & 1) + i) * 112 + J * 14 + col] = hn;
      }
    }
  };

  // flush ring -> global bf16 hi plane (full 64B lines)
  auto flushY8 = [&](int sBase) {
    const int sq = lane >> 2, part = lane & 3;
#pragma unroll
    for (int rr = 0; rr < 2; ++rr) {
      const int r = 2 * part + rr;  // slot = step offset within the block
      const int tg = dir ? (63 - (sBase + r)) : (sBase + r);
      const unsigned* src =
          ringD + ((unsigned)(w * 8 + r) * SEQPW + (unsigned)sq) * 12u;
      const uint4 h0 = *(const uint4*)(src);
      const uint4 h1 = *(const uint4*)(src + 4);
      char* gph = (char*)yhiP + ((sb + (unsigned)sq) * 64u + (unsigned)tg) * 32u;
      *(uint4*)(gph) = h0; *(uint4*)(gph + 16) = h1;
    }
  };
  auto flushO = [&](int tbase) {  // fp32 out: 448B/seq contiguous, coalesced
    const int sq = lane >> 3, part = lane & 7;
    char* gp = (char*)yf + ((sb + (unsigned)sq) * 64u + (unsigned)tbase) * 56u;
    const float* src = fstw + sq * 112 + part;
#pragma unroll
    for (int m = 0; m < 14; ++m)
      *(float*)(gp + (part + 8 * m) * 4) = src[8 * m];
  };

  // x offset for step index k (clamped at the tail; clamped loads feed only
  // dead XCALC results)
  auto XO = [&](int k) { return voff0 + (k > 63 ? 63 : k) * dsx; };

  float fb0[8], fb1[8], fb2[8], fb3[8], fb4[8], fb5[8], fb6[8], fb7[8];
  unsigned ub0[4], ub1[4], ub2[4], ub3[4], ub4[4], ub5[4], ub6[4], ub7[4];
  f32x4 axP[4], axQ[4];

  LOADX(fb0, ub0, XO(0));
  LOADX(fb1, ub1, XO(1));
  LOADX(fb2, ub2, XO(2));
  LOADX(fb3, ub3, XO(3));
  LOADX(fb4, ub4, XO(4));
  XCALC(fb0, ub0, axP);  // ax for step 0

#pragma unroll 1
  for (int s = 0; s < T; s += 8) {
    LOADX(fb5, ub5, XO(s + 5));
    LOADX(fb6, ub6, XO(s + 6));
    STEP(icx<0>{}, fb1, ub1, axP, axQ);
    STEP(icx<1>{}, fb2, ub2, axQ, axP);
    LOADX(fb7, ub7, XO(s + 7));
    LOADX(fb0, ub0, XO(s + 8));
    STEP(icx<2>{}, fb3, ub3, axP, axQ);
    STEP(icx<3>{}, fb4, ub4, axQ, axP);
    LOADX(fb1, ub1, XO(s + 9));
    LOADX(fb2, ub2, XO(s + 10));
    STEP(icx<4>{}, fb5, ub5, axP, axQ);
    STEP(icx<5>{}, fb6, ub6, axQ, axP);
    LOADX(fb3, ub3, XO(s + 11));
    LOADX(fb4, ub4, XO(s + 12));
    STEP(icx<6>{}, fb7, ub7, axP, axQ);
    STEP(icx<7>{}, fb0, ub0, axQ, axP);
    if constexpr (OUTM == 0) flushY8(s); else flushO(s);
  }
}

extern "C" void kernel_launch(void* const* d_in, const int* in_sizes, int n_in,
                              void* d_out, int out_size, void* d_ws, size_t ws_size,
                              hipStream_t stream) {
  const float* x     = (const float*)d_in[0];
  const float* wih1f = (const float*)d_in[1];
  const float* whh1f = (const float*)d_in[2];
  const float* bih1f = (const float*)d_in[3];
  const float* bhh1f = (const float*)d_in[4];
  const float* wih1b = (const float*)d_in[5];
  const float* whh1b = (const float*)d_in[6];
  const float* bih1b = (const float*)d_in[7];
  const float* bhh1b = (const float*)d_in[8];
  const float* wih2f = (const float*)d_in[9];
  const float* whh2f = (const float*)d_in[10];
  const float* bih2f = (const float*)d_in[11];
  const float* bhh2f = (const float*)d_in[12];
  const float* wih2b = (const float*)d_in[13];
  const float* whh2b = (const float*)d_in[14];
  const float* bih2b = (const float*)d_in[15];
  const float* bhh2b = (const float*)d_in[16];
  const float* wih3  = (const float*)d_in[17];
  const float* whh3  = (const float*)d_in[18];
  const float* bih3  = (const float*)d_in[19];
  const float* bhh3  = (const float*)d_in[20];

  using usp = unsigned short*;
  const size_t PL = (size_t)BATCH * T * 16;  // ushorts per plane (padded 16ch)
  usp y1fh = (usp)d_ws;
  usp y1bh = y1fh + PL;
  usp y2fh = y1bh + PL;
  usp y2bh = y2fh + PL;
  float* out = (float*)d_out;

  const dim3 blk(256);
  const dim3 grid_bi(BATCH / 64, 2);
  const dim3 grid_uni(BATCH / 32, 1);  // SEQPW=8 -> 2 waves/SIMD

  lstm_k<0, 0, 16><<<grid_bi, blk, 0, stream>>>(
      x, nullptr, nullptr,
      wih1f, whh1f, bih1f, bhh1f, wih1b, whh1b, bih1b, bhh1b,
      y1fh, y1bh, nullptr);
  lstm_k<1, 0, 16><<<grid_bi, blk, 0, stream>>>(
      nullptr, y1fh, y1bh,
      wih2f, whh2f, bih2f, bhh2f, wih2b, whh2b, bih2b, bhh2b,
      y2fh, y2bh, nullptr);
  lstm_k<1, 1, 8><<<grid_uni, blk, 0, stream>>>(
      nullptr, y2fh, y2bh,
      wih3, whh3, bih3, bhh3, wih3, whh3, bih3, bhh3,
      nullptr, nullptr, out);
}